// Round 12
// baseline (852.098 us; speedup 1.0000x reference)
//
#include <hip/hip_runtime.h>

#define N_ 6144
#define L_ 1024
#define D_ 512
#define H_ 256
#define SPARSE_MAX 64u

typedef unsigned char u8;
typedef unsigned short u16;
typedef unsigned long long u64;
typedef long long i64;
typedef __attribute__((ext_vector_type(4))) float f32x4;
typedef __attribute__((ext_vector_type(8))) short s16x8;
typedef __attribute__((ext_vector_type(4))) short s16x4;

__device__ __forceinline__ u16 f2b(float f){
  unsigned u = __float_as_uint(f);
  u += 0x7FFFu + ((u >> 16) & 1u);
  return (u16)(u >> 16);
}
__device__ __forceinline__ float b2f(u16 h){ return __uint_as_float(((unsigned)h) << 16); }
// fp32 -> OCP e4m3fn with RNE, clamp to +-448
__device__ __forceinline__ u8 f2e4(float x){
  float ax = fabsf(x);
  u8 s = (x < 0.0f) ? 0x80 : 0;
  ax = fminf(ax, 448.0f);
  if (ax < 0.015625f){                 // subnormal: m * 2^-9
    int m = (int)rintf(ax * 512.0f);   // 0..8 (8 == first normal, enc 0x08)
    return s | (u8)m;
  }
  unsigned b = __float_as_uint(ax);
  int e = (int)(b >> 23) - 127;
  unsigned mant = b & 0x7FFFFFu;
  unsigned r = mant + ((1u<<19) - 1u) + ((mant >> 20) & 1u);
  unsigned mq = r >> 20;               // 3 bits + carry
  if (mq & 8u){ mq = 0; e++; }
  if (e > 8){ e = 8; mq = 6; }         // 448
  return s | (u8)(((e + 7) << 3) | (mq & 7u));
}
__device__ __forceinline__ unsigned fkey(float f){
  unsigned u = __float_as_uint(f);
  return (u & 0x80000000u) ? ~u : (u | 0x80000000u);
}
__device__ __forceinline__ float funkey(unsigned k){
  unsigned u = (k & 0x80000000u) ? (k & 0x7FFFFFFFu) : ~k;
  return __uint_as_float(u);
}
__device__ __forceinline__ float wave_sum(float v){
  #pragma unroll
  for(int o=32;o;o>>=1) v += __shfl_xor(v,o);
  return v;
}
__device__ __forceinline__ float wave_max(float v){
  #pragma unroll
  for(int o=32;o;o>>=1) v = fmaxf(v,__shfl_xor(v,o));
  return v;
}
__device__ __forceinline__ float wave_min(float v){
  #pragma unroll
  for(int o=32;o;o>>=1) v = fminf(v,__shfl_xor(v,o));
  return v;
}
__device__ __forceinline__ float blk_sum256(float v){
  __shared__ float sm[4];
  v = wave_sum(v);
  __syncthreads();
  if((threadIdx.x&63)==0) sm[threadIdx.x>>6]=v;
  __syncthreads();
  return sm[0]+sm[1]+sm[2]+sm[3];
}
__device__ __forceinline__ float blk_min256(float v){
  __shared__ float sm[4];
  v = wave_min(v);
  __syncthreads();
  if((threadIdx.x&63)==0) sm[threadIdx.x>>6]=v;
  __syncthreads();
  return fminf(fminf(sm[0],sm[1]),fminf(sm[2],sm[3]));
}
__device__ __forceinline__ float blk_max256(float v){
  __shared__ float sm[4];
  v = wave_max(v);
  __syncthreads();
  if((threadIdx.x&63)==0) sm[threadIdx.x>>6]=v;
  __syncthreads();
  return fmaxf(fmaxf(sm[0],sm[1]),fmaxf(sm[2],sm[3]));
}

template<int VW> __device__ __forceinline__ void waitv(){
  if constexpr(VW==8) asm volatile("s_waitcnt vmcnt(8)" ::: "memory");
  else if constexpr(VW==4) asm volatile("s_waitcnt vmcnt(4)" ::: "memory");
  else asm volatile("s_waitcnt vmcnt(0)" ::: "memory");
}

// ---------------- bf16 128x128 GEMM (unchanged structure) ------------------
#define STG4(bb,k0) do{ \
  __builtin_amdgcn_global_load_lds((__attribute__((address_space(1))) void*)(gA0+(k0)), (__attribute__((address_space(3))) void*)(lds + (bb)*4096 + (wid<<9)),        16, 0, 0); \
  __builtin_amdgcn_global_load_lds((__attribute__((address_space(1))) void*)(gA1+(k0)), (__attribute__((address_space(3))) void*)(lds + (bb)*4096 + 2048 + (wid<<9)), 16, 0, 0); \
  __builtin_amdgcn_global_load_lds((__attribute__((address_space(1))) void*)(gB0+(k0)), (__attribute__((address_space(3))) void*)(lds + 12288 + (bb)*4096 + (wid<<9)),        16, 0, 0); \
  __builtin_amdgcn_global_load_lds((__attribute__((address_space(1))) void*)(gB1+(k0)), (__attribute__((address_space(3))) void*)(lds + 12288 + (bb)*4096 + 2048 + (wid<<9)), 16, 0, 0); \
}while(0)

__global__ __launch_bounds__(256) void gemm_bt(
  const u16* __restrict__ A, const u16* __restrict__ Bt,
  int M, int Nc, int K,
  u16* __restrict__ Cb, const unsigned* __restrict__ gate)
{
  if (gate && gate[2] <= SPARSE_MAX) return;
  __shared__ __align__(16) u16 lds[3*4096*2];   // 48 KB
  const int tid = threadIdx.x;
  const int wid = tid>>6, lane = tid&63;

  const int gx = gridDim.x;
  int lid = blockIdx.y*gx + blockIdx.x;
  const int nwg = gx*gridDim.y;
  if ((nwg & 7) == 0) {
    const int chunk = nwg >> 3;
    lid = (lid & 7)*chunk + (lid >> 3);
  }
  const int m0 = (lid/gx)<<7, n0 = (lid%gx)<<7;
  const int wr = wid>>1, wc = wid&1;

  const int Klen = K / gridDim.z;
  const int kbeg = blockIdx.z * Klen;

  const int srow = (wid<<4) + (lane>>2);
  const int scol = (lane&3)<<3;
  const u16* gA0 = A  + (size_t)(m0+srow   )*K + scol;
  const u16* gA1 = A  + (size_t)(m0+srow+64)*K + scol;
  const u16* gB0 = Bt + (size_t)(n0+srow   )*K + scol;
  const u16* gB1 = Bt + (size_t)(n0+srow+64)*K + scol;

  f32x4 acc[4][4] = {};
  const int lr = lane&15, lk = (lane>>4)<<3;

  const int NIT = Klen>>5;   // >= 3 required
  STG4(0, kbeg);
  STG4(1, kbeg+32);
  STG4(2, kbeg+64);

  for (int it=0; it<NIT-2; ++it){
    const int b = it - (it/3)*3;
    waitv<8>();
    __builtin_amdgcn_s_barrier();
    const u16* baseA = lds + b*4096;
    const u16* baseB = lds + 12288 + b*4096;
    s16x8 af[4], bfr[4];
    #pragma unroll
    for(int m=0;m<4;m++) af[m]  = *(const s16x8*)(baseA + ((wr<<6)+(m<<4)+lr)*32 + lk);
    #pragma unroll
    for(int n=0;n<4;n++) bfr[n] = *(const s16x8*)(baseB + ((wc<<6)+(n<<4)+lr)*32 + lk);
    asm volatile("s_waitcnt lgkmcnt(0)" ::: "memory");
    __builtin_amdgcn_sched_barrier(0);
    __builtin_amdgcn_s_barrier();
    if (it+3 < NIT) STG4(b, kbeg + ((it+3)<<5));
    #pragma unroll
    for(int m=0;m<4;m++)
      #pragma unroll
      for(int n=0;n<4;n++)
        acc[m][n] = __builtin_amdgcn_mfma_f32_16x16x32_bf16(af[m], bfr[n], acc[m][n], 0,0,0);
  }
  #pragma unroll
  for (int tail=0; tail<2; ++tail){
    const int it = NIT-2+tail; const int b = it - (it/3)*3;
    if (tail==0) waitv<4>(); else waitv<0>();
    __builtin_amdgcn_s_barrier();
    const u16* baseA = lds + b*4096;
    const u16* baseB = lds + 12288 + b*4096;
    s16x8 af[4], bfr[4];
    #pragma unroll
    for(int m=0;m<4;m++) af[m]  = *(const s16x8*)(baseA + ((wr<<6)+(m<<4)+lr)*32 + lk);
    #pragma unroll
    for(int n=0;n<4;n++) bfr[n] = *(const s16x8*)(baseB + ((wc<<6)+(n<<4)+lr)*32 + lk);
    #pragma unroll
    for(int m=0;m<4;m++)
      #pragma unroll
      for(int n=0;n<4;n++)
        acc[m][n] = __builtin_amdgcn_mfma_f32_16x16x32_bf16(af[m], bfr[n], acc[m][n], 0,0,0);
  }

  __syncthreads();
  u16* lC = lds;
  {
    const int rb_l = (wr<<6) + ((lane>>4)<<2);
    const int cb_l = (wc<<6) + lr;
    #pragma unroll
    for(int m=0;m<4;m++)
      #pragma unroll
      for(int n=0;n<4;n++){
        f32x4 v = acc[m][n];
        #pragma unroll
        for(int e=0;e<4;e++)
          lC[(rb_l+(m<<4)+e)*128 + cb_l+(n<<4)] = f2b(v[e]);
      }
  }
  __syncthreads();
  u16* Cp = Cb + (size_t)blockIdx.z * M * Nc;
  #pragma unroll
  for(int q=0;q<8;q++){
    int c = (q<<8) + tid;
    int r = c>>4, cc = (c&15)<<3;
    *(s16x8*)(Cp + (size_t)(m0+r)*Nc + n0 + cc) = *(const s16x8*)(lC + r*128 + cc);
  }
}

// ---------------- fp8 128x128 GEMM, BK=64 (gram + ga adjacency) ------------
// A[M,K], Bt[Nc,K] fp8-e4m3 row-major. Same 3-buffer counted pipeline; half
// the iterations/barriers/stage-instrs of the bf16 version.
// MODE 0: bf16 plane z (values carry producer scales; descale in consumer).
// MODE 1 (gram): balanced upper-triangle grid + NT store + min/max atomics.
#define STG8(bb,k0) do{ \
  __builtin_amdgcn_global_load_lds((__attribute__((address_space(1))) void*)(gA0+(k0)),                 (__attribute__((address_space(3))) void*)(lds8 + (bb)*8192 + (wid<<11)),        16, 0, 0); \
  __builtin_amdgcn_global_load_lds((__attribute__((address_space(1))) void*)(gA0+(size_t)16*K+(k0)),    (__attribute__((address_space(3))) void*)(lds8 + (bb)*8192 + (wid<<11) + 1024), 16, 0, 0); \
  __builtin_amdgcn_global_load_lds((__attribute__((address_space(1))) void*)(gB0+(k0)),                 (__attribute__((address_space(3))) void*)(lds8 + 24576 + (bb)*8192 + (wid<<11)),        16, 0, 0); \
  __builtin_amdgcn_global_load_lds((__attribute__((address_space(1))) void*)(gB0+(size_t)16*K+(k0)),    (__attribute__((address_space(3))) void*)(lds8 + 24576 + (bb)*8192 + (wid<<11) + 1024), 16, 0, 0); \
}while(0)

template<int MODE>
__global__ __launch_bounds__(256) void gemm_f8(
  const u8* __restrict__ A, const u8* __restrict__ Bt,
  int M, int Nc, int K,
  u16* __restrict__ Cb, unsigned* __restrict__ mmx)
{
  __shared__ __align__(16) u8 lds8[3*8192*2];   // 48 KB
  const int tid = threadIdx.x;
  const int wid = tid>>6, lane = tid&63;

  int m0, n0;
  if (MODE==1){
    int t = (int)blockIdx.x;
    t = (t&7)*147 + (t>>3);
    int i=0, rem=t;
    while (rem >= 48-i){ rem -= 48-i; ++i; }
    m0 = i<<7; n0 = (i+rem)<<7;
  } else {
    const int gx = gridDim.x;
    int lid = blockIdx.y*gx + blockIdx.x;
    const int nwg = gx*gridDim.y;
    if ((nwg & 7) == 0){ const int chunk = nwg>>3; lid = (lid&7)*chunk + (lid>>3); }
    m0 = (lid/gx)<<7; n0 = (lid%gx)<<7;
  }
  const int wr = wid>>1, wc = wid&1;

  const int Klen = K / gridDim.z;
  const int kbeg = blockIdx.z * Klen;

  // staging: per wave 32 rows of 64B via 2 instrs (16 rows each)
  const u8* gA0 = A  + (size_t)(m0 + (wid<<5) + (lane>>2))*K + ((lane&3)<<4);
  const u8* gB0 = Bt + (size_t)(n0 + (wid<<5) + (lane>>2))*K + ((lane&3)<<4);

  f32x4 acc[4][4] = {};
  const int lr = lane&15, lk8 = (lane>>4)<<3;   // byte offset of 8-elem chunk

  const int NIT = Klen>>6;   // BK=64; >= 3 required
  STG8(0, kbeg);
  STG8(1, kbeg+64);
  STG8(2, kbeg+128);

  for (int it=0; it<NIT-2; ++it){
    const int b = it - (it/3)*3;
    waitv<8>();
    __builtin_amdgcn_s_barrier();
    const u8* baseA = lds8 + b*8192;
    const u8* baseB = lds8 + 24576 + b*8192;
    i64 af[4][2], bfr[4][2];
    #pragma unroll
    for(int m=0;m<4;m++){
      const u8* p = baseA + ((wr<<6)+(m<<4)+lr)*64 + lk8;
      af[m][0] = *(const i64*)p; af[m][1] = *(const i64*)(p+32);
    }
    #pragma unroll
    for(int n=0;n<4;n++){
      const u8* p = baseB + ((wc<<6)+(n<<4)+lr)*64 + lk8;
      bfr[n][0] = *(const i64*)p; bfr[n][1] = *(const i64*)(p+32);
    }
    asm volatile("s_waitcnt lgkmcnt(0)" ::: "memory");
    __builtin_amdgcn_sched_barrier(0);
    __builtin_amdgcn_s_barrier();
    if (it+3 < NIT) STG8(b, kbeg + ((it+3)<<6));
    #pragma unroll
    for(int m=0;m<4;m++)
      #pragma unroll
      for(int n=0;n<4;n++){
        acc[m][n] = __builtin_amdgcn_mfma_f32_16x16x32_fp8_fp8(af[m][0], bfr[n][0], acc[m][n], 0,0,0);
        acc[m][n] = __builtin_amdgcn_mfma_f32_16x16x32_fp8_fp8(af[m][1], bfr[n][1], acc[m][n], 0,0,0);
      }
  }
  #pragma unroll
  for (int tail=0; tail<2; ++tail){
    const int it = NIT-2+tail; const int b = it - (it/3)*3;
    if (tail==0) waitv<4>(); else waitv<0>();
    __builtin_amdgcn_s_barrier();
    const u8* baseA = lds8 + b*8192;
    const u8* baseB = lds8 + 24576 + b*8192;
    i64 af[4][2], bfr[4][2];
    #pragma unroll
    for(int m=0;m<4;m++){
      const u8* p = baseA + ((wr<<6)+(m<<4)+lr)*64 + lk8;
      af[m][0] = *(const i64*)p; af[m][1] = *(const i64*)(p+32);
    }
    #pragma unroll
    for(int n=0;n<4;n++){
      const u8* p = baseB + ((wc<<6)+(n<<4)+lr)*64 + lk8;
      bfr[n][0] = *(const i64*)p; bfr[n][1] = *(const i64*)(p+32);
    }
    #pragma unroll
    for(int m=0;m<4;m++)
      #pragma unroll
      for(int n=0;n<4;n++){
        acc[m][n] = __builtin_amdgcn_mfma_f32_16x16x32_fp8_fp8(af[m][0], bfr[n][0], acc[m][n], 0,0,0);
        acc[m][n] = __builtin_amdgcn_mfma_f32_16x16x32_fp8_fp8(af[m][1], bfr[n][1], acc[m][n], 0,0,0);
      }
  }

  float tmin = 3.0e38f, tmax = -3.0e38f;
  if (MODE==1){
    #pragma unroll
    for(int m=0;m<4;m++)
      #pragma unroll
      for(int n=0;n<4;n++){
        f32x4 v = acc[m][n];
        #pragma unroll
        for(int e=0;e<4;e++){ tmin = fminf(tmin,v[e]); tmax = fmaxf(tmax,v[e]); }
      }
  }

  __syncthreads();
  u16* lC = (u16*)lds8;
  {
    const int rb_l = (wr<<6) + ((lane>>4)<<2);
    const int cb_l = (wc<<6) + lr;
    #pragma unroll
    for(int m=0;m<4;m++)
      #pragma unroll
      for(int n=0;n<4;n++){
        f32x4 v = acc[m][n];
        #pragma unroll
        for(int e=0;e<4;e++)
          lC[(rb_l+(m<<4)+e)*128 + cb_l+(n<<4)] = f2b(v[e]);
      }
  }
  __syncthreads();
  u16* Cp = (MODE==0) ? (Cb + (size_t)blockIdx.z * M * Nc) : Cb;
  #pragma unroll
  for(int q=0;q<8;q++){
    int c = (q<<8) + tid;
    int r = c>>4, cc = (c&15)<<3;
    s16x8 v = *(const s16x8*)(lC + r*128 + cc);
    if (MODE==1)
      __builtin_nontemporal_store(v, (s16x8*)(Cp + (size_t)(m0+r)*Nc + n0 + cc));
    else
      *(s16x8*)(Cp + (size_t)(m0+r)*Nc + n0 + cc) = v;
  }

  if (MODE==1){
    tmin = wave_min(tmin); tmax = wave_max(tmax);
    __shared__ float rmn[4], rmx[4];
    if(lane==0){ rmn[wid]=tmin; rmx[wid]=tmax; }
    __syncthreads();
    if(tid==0){
      float mn=fminf(fminf(rmn[0],rmn[1]),fminf(rmn[2],rmn[3]));
      float mx=fmaxf(fmaxf(rmx[0],rmx[1]),fmaxf(rmx[2],rmx[3]));
      atomicMin(mmx+0, fkey(mn));
      atomicMax(mmx+1, fkey(mx));
    }
  }
}

// DENSE-FALLBACK ONLY: copy strictly-upper 128-blocks of C to lower, transposed
__global__ __launch_bounds__(256) void mirror_lower(u16* __restrict__ C,
  const unsigned* __restrict__ gate)
{
  if (gate[2] <= SPARSE_MAX) return;
  int c0 = blockIdx.x<<5, r0 = blockIdx.y<<5;
  if ((r0>>7) >= (c0>>7)) return;
  __shared__ u16 t[32][33];
  int tx = threadIdx.x&31, ty = threadIdx.x>>5;
  #pragma unroll
  for(int i=0;i<32;i+=8) t[ty+i][tx] = C[(size_t)(r0+ty+i)*N_ + c0+tx];
  __syncthreads();
  #pragma unroll
  for(int i=0;i<32;i+=8)
    __builtin_nontemporal_store(t[tx][ty+i], C + (size_t)(c0+ty+i)*N_ + r0+tx);
}

// batched weight-prep transposes: fp32 [R][C] -> bf16 [C][R], 12 descriptors
struct TDesc { const float* src; u16* dst; int R; int C; int base; };
struct TDescs { TDesc d[12]; };
__global__ __launch_bounds__(256) void transpose_cast_multi(TDescs ds, int nd)
{
  int b = (int)blockIdx.x;
  int k = 0;
  for (int q=1;q<nd;q++) if (b >= ds.d[q].base) k = q;
  const float* src = ds.d[k].src;
  u16* dst = ds.d[k].dst;
  int R = ds.d[k].R, C = ds.d[k].C;
  int lt = b - ds.d[k].base;
  int tc = C>>5;
  int bx = lt % tc, by = lt / tc;
  __shared__ float t[32][33];
  int c0 = bx<<5, r0 = by<<5;
  int tx = threadIdx.x&31, ty = threadIdx.x>>5;
  #pragma unroll
  for(int i=0;i<32;i+=8) t[ty+i][tx] = src[(size_t)(r0+ty+i)*C + c0+tx];
  __syncthreads();
  #pragma unroll
  for(int i=0;i<32;i+=8) dst[(size_t)(c0+ty+i)*R + r0+tx] = f2b(t[tx][ty+i]);
}

// dst[C][R] bf16 = transpose( sum_p bf16_plane_p [R][C] ); gated (dense path)
__global__ __launch_bounds__(256) void transpose_sum_bf(
  const u16* __restrict__ src, size_t pstr, int nsp,
  u16* __restrict__ dst, int R, int C, const unsigned* __restrict__ gate)
{
  if (gate && gate[2] <= SPARSE_MAX) return;
  __shared__ float t[32][33];
  int c0 = blockIdx.x<<5, r0 = blockIdx.y<<5;
  int tx = threadIdx.x&31, ty = threadIdx.x>>5;
  #pragma unroll
  for(int i=0;i<32;i+=8){
    float v = 0;
    for(int p=0;p<nsp;p++)
      v += b2f(src[(size_t)p*pstr + (size_t)(r0+ty+i)*C + c0+tx]);
    t[ty+i][tx] = v;
  }
  __syncthreads();
  #pragma unroll
  for(int i=0;i<32;i+=8) dst[(size_t)(c0+ty+i)*R + r0+tx] = f2b(t[tx][ty+i]);
}

// dst[C][R] FP8 (scale 4) = transpose( sum_p bf16_plane_p [R][C] )
__global__ __launch_bounds__(256) void transpose_sum_f8(
  const u16* __restrict__ src, size_t pstr, int nsp,
  u8* __restrict__ dst, int R, int C)
{
  __shared__ float t[32][33];
  int c0 = blockIdx.x<<5, r0 = blockIdx.y<<5;
  int tx = threadIdx.x&31, ty = threadIdx.x>>5;
  #pragma unroll
  for(int i=0;i<32;i+=8){
    float v = 0;
    for(int p=0;p<nsp;p++)
      v += b2f(src[(size_t)p*pstr + (size_t)(r0+ty+i)*C + c0+tx]);
    t[ty+i][tx] = v;
  }
  __syncthreads();
  #pragma unroll
  for(int i=0;i<32;i+=8) dst[(size_t)(c0+ty+i)*R + r0+tx] = f2e4(t[tx][ty+i] * 4.0f);
}

// prep: XB bf16; XN8 fp8 of row-L2-normalized x, scale 16
__global__ __launch_bounds__(256) void prep_x(const float* __restrict__ x,
  u16* __restrict__ xb, u8* __restrict__ xn8)
{
  int row = blockIdx.x, t = threadIdx.x;
  const float* p = x + (size_t)row*L_ + (t<<2);
  f32x4 v = *(const f32x4*)p;
  float ss = v[0]*v[0]+v[1]*v[1]+v[2]*v[2]+v[3]*v[3];
  float tot = blk_sum256(ss);
  float inv = 16.0f/fmaxf(sqrtf(tot), 1e-12f);
  u16* pb = xb + (size_t)row*L_ + (t<<2);
  u16 ob[4]; u8 o8[4];
  #pragma unroll
  for(int k=0;k<4;k++){ ob[k]=f2b(v[k]); o8[k]=f2e4(v[k]*inv); }
  *(s16x4*)pb = *(s16x4*)ob;
  *(unsigned*)(xn8 + (size_t)row*L_ + (t<<2)) = *(unsigned*)o8;
}

// fused-projection epilogue: a at cols [0,256), b at [256,512) of [N,1536] planes
__global__ __launch_bounds__(256) void attn_epi(const u16* __restrict__ SPA,
  size_t pstr, int nsp,
  const float* __restrict__ ba, const float* __restrict__ bb,
  const float* __restrict__ wc, const float* __restrict__ bc,
  float* __restrict__ agg, float* __restrict__ s)
{
  int row = (blockIdx.x<<2) + (threadIdx.x>>6);
  int lane = threadIdx.x&63;
  float a[4]={0,0,0,0}, b[4]={0,0,0,0};
  for(int p=0;p<nsp;p++){
    s16x4 ua = *(const s16x4*)(SPA + (size_t)p*pstr + (size_t)row*1536 + (lane<<2));
    s16x4 ub = *(const s16x4*)(SPA + (size_t)p*pstr + (size_t)row*1536 + 256 + (lane<<2));
    #pragma unroll
    for(int j=0;j<4;j++){ a[j]+=b2f((u16)ua[j]); b[j]+=b2f((u16)ub[j]); }
  }
  float acc=0;
  #pragma unroll
  for(int j=0;j<4;j++){
    int h = (lane<<2)+j;
    float tv = tanhf(a[j]+ba[h]);
    float sg = 1.0f/(1.0f+expf(-(b[j]+bb[h])));
    acc += tv*sg*wc[h];
  }
  acc = wave_sum(acc);
  if(lane==0){
    float v = acc + bc[0];
    agg[row]=v;
    s[row]=1.0f/(1.0f+expf(-v));
  }
}

// single-block min/max of s
__global__ __launch_bounds__(256) void s_stats(const float* __restrict__ s, float* __restrict__ sc){
  int t=threadIdx.x;
  float mn=3e38f, mx=-3e38f;
  for(int i=t;i<N_;i+=256){ float v=s[i]; mn=fminf(mn,v); mx=fmaxf(mx,v); }
  float MN=blk_min256(mn);
  float MX=blk_max256(mx);
  if(t==0){ sc[0]=MN; sc[1]=MX; }
}

// aw -> FP8 (scale 2048), l1-row-normalized; packed u32 NT stores
__global__ __launch_bounds__(256) void aw_write(const float* __restrict__ maps, const float* __restrict__ s,
  const float* __restrict__ sc, u8* __restrict__ aw8)
{
  int i = blockIdx.x, t = threadIdx.x;
  float smin = sc[0], smax = sc[1];
  float mn = smin*smin, mx = smax*smax;
  float beta = 0.6f/(mx-mn);
  float c1 = 0.4f - beta*mn;
  float si = s[i];
  const float* mrow = maps + (size_t)i*N_;
  float mv[6][4];
  float part = 0;
  #pragma unroll
  for(int q=0;q<6;q++){
    int j = (t<<2) + (q<<10);
    f32x4 mm = *(const f32x4*)(mrow + j);
    f32x4 sv = *(const f32x4*)(s + j);
    #pragma unroll
    for(int e=0;e<4;e++){ mv[q][e] = c1 + beta*si*sv[e] + mm[e]; part += mv[q][e]; }
  }
  float r = blk_sum256(part);
  float inv = 2048.0f/fmaxf(r, 1e-12f);
  u8* orow = aw8 + (size_t)i*N_;
  #pragma unroll
  for(int q=0;q<6;q++){
    u8 o[4];
    #pragma unroll
    for(int e=0;e<4;e++) o[e] = f2e4(mv[q][e]*inv);
    __builtin_nontemporal_store(*(unsigned*)o, (unsigned*)(orow + (t<<2) + (q<<10)));
  }
}

// out = relu(LN( (sum_p Y_p)*ds*rowscale + bias )).  Dense path only.
__global__ __launch_bounds__(256) void ln_epi512(const u16* __restrict__ Y, size_t pstr, int nsp,
  int rs, int cbase, float dsc,
  const float* __restrict__ ki,
  const float* __restrict__ bias, const float* __restrict__ g, const float* __restrict__ bn,
  u16* __restrict__ outb,
  const unsigned* __restrict__ gate)
{
  if (gate && gate[2] <= SPARSE_MAX) return;
  int row = (blockIdx.x<<2)+(threadIdx.x>>6);
  int lane = threadIdx.x&63;
  int c0 = lane<<3;
  float v[8] = {0,0,0,0,0,0,0,0};
  for(int p=0;p<nsp;p++){
    s16x8 u = *(const s16x8*)(Y + (size_t)p*pstr + (size_t)row*rs + cbase + c0);
    #pragma unroll
    for(int j=0;j<8;j++) v[j] += b2f((u16)u[j]);
  }
  float scale = dsc * (ki ? (1.0f/ki[row]) : 1.0f);
  float sum=0, ssum=0;
  #pragma unroll
  for(int j=0;j<8;j++){ v[j] = v[j]*scale + bias[c0+j]; sum+=v[j]; ssum+=v[j]*v[j]; }
  sum = wave_sum(sum); ssum = wave_sum(ssum);
  float m = sum*(1.0f/D_);
  float var = ssum*(1.0f/D_) - m*m;
  float invsd = rsqrtf(var + 1e-5f);
  u16 ob[8];
  #pragma unroll
  for(int j=0;j<8;j++){
    float o = (v[j]-m)*invsd*g[c0+j] + bn[c0+j];
    o = fmaxf(o, 0.0f);
    ob[j] = f2b(o);
  }
  *(s16x8*)(outb + (size_t)row*D_ + c0) = *(s16x8*)ob;
}

// both proj LNs in one launch
__global__ __launch_bounds__(256) void ln_epi_proj(const u16* __restrict__ Y, size_t pstr, int nsp,
  const float* __restrict__ b1, const float* __restrict__ g1, const float* __restrict__ n1, u16* __restrict__ o1,
  const float* __restrict__ b0, const float* __restrict__ g0, const float* __restrict__ n0, u16* __restrict__ o0)
{
  const int sel = blockIdx.y;
  const int cbase = sel ? 512 : 1024;
  const float* bias = sel ? b0 : b1;
  const float* g    = sel ? g0 : g1;
  const float* bn   = sel ? n0 : n1;
  u16* outb         = sel ? o0 : o1;
  int row = (blockIdx.x<<2)+(threadIdx.x>>6);
  int lane = threadIdx.x&63;
  int c0 = lane<<3;
  float v[8] = {0,0,0,0,0,0,0,0};
  for(int p=0;p<nsp;p++){
    s16x8 u = *(const s16x8*)(Y + (size_t)p*pstr + (size_t)row*1536 + cbase + c0);
    #pragma unroll
    for(int j=0;j<8;j++) v[j] += b2f((u16)u[j]);
  }
  float sum=0, ssum=0;
  #pragma unroll
  for(int j=0;j<8;j++){ v[j] = v[j] + bias[c0+j]; sum+=v[j]; ssum+=v[j]*v[j]; }
  sum = wave_sum(sum); ssum = wave_sum(ssum);
  float m = sum*(1.0f/D_);
  float var = ssum*(1.0f/D_) - m*m;
  float invsd = rsqrtf(var + 1e-5f);
  u16 ob[8];
  #pragma unroll
  for(int j=0;j<8;j++){
    float o = (v[j]-m)*invsd*g[c0+j] + bn[c0+j];
    o = fmaxf(o, 0.0f);
    ob[j] = f2b(o);
  }
  *(s16x8*)(outb + (size_t)row*D_ + c0) = *(s16x8*)ob;
}

__global__ __launch_bounds__(256) void bias_cast(const u16* __restrict__ Y, size_t pstr, int nsp,
  const float* __restrict__ b, u16* __restrict__ outb)
{
  size_t idx = ((size_t)blockIdx.x*256 + threadIdx.x)<<3;
  float v[8] = {0,0,0,0,0,0,0,0};
  for(int p=0;p<nsp;p++){
    s16x8 u = *(const s16x8*)(Y + (size_t)p*pstr + idx);
    #pragma unroll
    for(int j=0;j<8;j++) v[j] += b2f((u16)u[j]);
  }
  int c = (int)(idx & (D_-1));
  u16 ob[8];
  #pragma unroll
  for(int k=0;k<8;k++) ob[k] = f2b(v[k]+b[c+k]);
  *(s16x8*)(outb+idx) = *(s16x8*)ob;
}

__global__ void init_k(unsigned* mmx){
  mmx[0]=0xFFFFFFFFu; mmx[1]=0u; mmx[2]=0u;
}

// upper-triangle binarize (reads bf16 gram, lower half stale); BM pre-zeroed
__global__ __launch_bounds__(256) void binarize_tri(const u16* __restrict__ csb,
  const unsigned* __restrict__ mmx, u64* __restrict__ bm)
{
  int i = blockIdx.x, t = threadIdx.x;
  int lane = t&63, w = t>>6;
  float mn = funkey(mmx[0]), mx = funkey(mmx[1]);
  float th = mn + 0.5f*(mx-mn);
  const u16* row = csb + (size_t)i*N_;
  u64* bmrow = bm + (size_t)i*96;
  const int w0 = i>>6;
  for (int wq = w0 + w; wq < 96; wq += 4){
    int j = (wq<<6) + lane;
    bool on = (j >= i) && (b2f(row[j]) >= th);
    u64 mask = __ballot(on);
    if (lane == 0){
      if (wq == w0) atomicOr((u64*)(bmrow+wq), mask);
      else bmrow[wq] = mask;
    }
    if (on && j > i)
      atomicOr((u64*)(bm + (size_t)j*96 + w0), 1ull << (i&63));
  }
}

// finalize from completed bitmap: ki, z, max-nnz
__global__ __launch_bounds__(256) void binarize_fin(const u64* __restrict__ bm,
  unsigned* __restrict__ mmx, const float* __restrict__ agg,
  float* __restrict__ ki, float* __restrict__ z)
{
  int i = blockIdx.x, t = threadIdx.x;
  float cnt = 0, dot = 0;
  if (t < 96){
    u64 m = bm[(size_t)i*96 + t];
    cnt = (float)__popcll(m);
    while (m){
      int b = __ffsll((long long)m) - 1;
      m &= m - 1;
      dot += agg[(t<<6) + b];
    }
  }
  float k  = blk_sum256(cnt);
  float dt = blk_sum256(dot);
  if (t==0){
    ki[i] = k;
    float tr = dt/(k*sqrtf((float)N_));
    z[i] = 0.3f*tr + 0.7f*agg[i];
    if (k > (float)SPARSE_MAX)
      atomicMax(mmx+2, (unsigned)(k+0.5f));
  }
}

// dense-fallback only: rewrite gram in place as 0/1 bf16 (after mirror_lower)
__global__ __launch_bounds__(256) void binarize_store(u16* __restrict__ csb,
  const unsigned* __restrict__ mmx)
{
  if (mmx[2] <= SPARSE_MAX) return;
  int i = blockIdx.x, t = threadIdx.x;
  float mn = funkey(mmx[0]), mx = funkey(mmx[1]);
  float th = mn + 0.5f*(mx-mn);
  u16* row = csb + (size_t)i*N_;
  #pragma unroll
  for(int q=0;q<24;q++){
    int j = t + (q<<8);
    row[j] = (b2f(row[j]) >= th) ? (u16)0x3F80 : (u16)0;
  }
}

// sparse adjacency apply FUSED with LN epilogue
__global__ __launch_bounds__(256) void gather_ln(const u64* __restrict__ bm,
  const u16* __restrict__ SPp, size_t pstr, int nsp,
  const unsigned* __restrict__ gate, const float* __restrict__ ki,
  const float* __restrict__ bias, const float* __restrict__ g, const float* __restrict__ bn,
  u16* __restrict__ outb)
{
  if (gate[2] > SPARSE_MAX) return;
  int i = blockIdx.x, t = threadIdx.x;
  __shared__ u64 wbuf[96];
  __shared__ u16 idx[SPARSE_MAX];
  __shared__ int nn_s;
  if (t < 96) wbuf[t] = bm[(size_t)i*96 + t];
  __syncthreads();
  if (t == 0){
    int nn = 0;
    for(int k=0;k<96;k++){
      u64 m = wbuf[k];
      while(m && nn < (int)SPARSE_MAX){
        int b = __ffsll((long long)m) - 1;
        m &= m - 1;
        idx[nn++] = (u16)((k<<6) + b);
      }
    }
    nn_s = nn;
  }
  __syncthreads();
  int nn = nn_s;
  float a0=0, a1=0;
  for(int k=0;k<nn;k++){
    size_t jb = (size_t)idx[k]*512;
    for(int p=0;p<nsp;p++){
      a0 += b2f(SPp[p*pstr + jb + t]);
      a1 += b2f(SPp[p*pstr + jb + t + 256]);
    }
  }
  float scale = 1.0f/ki[i];
  float v0 = a0*scale + bias[t];
  float v1 = a1*scale + bias[t+256];
  float sum  = blk_sum256(v0+v1);
  float ssum = blk_sum256(v0*v0+v1*v1);
  float m = sum*(1.0f/512.0f);
  float var = ssum*(1.0f/512.0f) - m*m;
  float inv = rsqrtf(var+1e-5f);
  float o0 = fmaxf((v0-m)*inv*g[t]+bn[t], 0.0f);
  float o1 = fmaxf((v1-m)*inv*g[t+256]+bn[t+256], 0.0f);
  outb[(size_t)i*512 + t]       = f2b(o0);
  outb[(size_t)i*512 + t + 256] = f2b(o1);
}

__global__ __launch_bounds__(1024) void softmax_prep(const float* __restrict__ z,
  float* __restrict__ e, float* __restrict__ sexp)
{
  int t = threadIdx.x;
  __shared__ float sm[16];
  float mx=-3e38f;
  for(int i=t;i<N_;i+=1024) mx=fmaxf(mx,z[i]);
  mx = wave_max(mx);
  if((t&63)==0) sm[t>>6]=mx;
  __syncthreads();
  float zm = sm[0];
  #pragma unroll
  for(int w=1;w<16;w++) zm=fmaxf(zm,sm[w]);
  __syncthreads();
  float sum=0;
  for(int i=t;i<N_;i+=1024){ float ee=expf(z[i]-zm); e[i]=ee; sum+=ee; }
  sum = wave_sum(sum);
  if((t&63)==0) sm[t>>6]=sum;
  __syncthreads();
  if(t==0){ float S=0; for(int w=0;w<16;w++) S+=sm[w]; *sexp=S; }
}

__global__ __launch_bounds__(256) void pooled_partial(const float* __restrict__ e,
  const u16* __restrict__ g2b, const u16* __restrict__ g1b, float* __restrict__ part)
{
  int b = blockIdx.x, t = threadIdx.x;
  float a0=0,a1=0,a2=0,a3=0;
  for(int r=0;r<192;r++){
    int row = b*192+r;
    float w = e[row];
    a0 += w * b2f(g2b[(size_t)row*D_ + t]);
    a1 += w * b2f(g2b[(size_t)row*D_ + t+256]);
    a2 += w * b2f(g1b[(size_t)row*D_ + t]);
    a3 += w * b2f(g1b[(size_t)row*D_ + t+256]);
  }
  part[(size_t)b*1024 + t]      = a0;
  part[(size_t)b*1024 + t+256]  = a1;
  part[(size_t)b*1024 + t+512]  = a2;
  part[(size_t)b*1024 + t+768]  = a3;
}

__global__ __launch_bounds__(1024) void final_k(const float* __restrict__ part, const float* __restrict__ sexp,
  const float* __restrict__ lng, const float* __restrict__ lnb,
  const float* __restrict__ clsw, float* __restrict__ out)
{
  int t = threadIdx.x;
  __shared__ float red[16];
  __shared__ float smv[1024];
  __shared__ float lgs[4];
  float p=0;
  for(int b=0;b<32;b++) p += part[b*1024 + t];
  p /= sexp[0];
  float w = wave_sum(p);
  if((t&63)==0) red[t>>6]=w;
  __syncthreads();
  float tot=0;
  #pragma unroll
  for(int i2=0;i2<16;i2++) tot+=red[i2];
  float m = tot*(1.0f/1024.0f);
  __syncthreads();
  float d = p-m;
  w = wave_sum(d*d);
  if((t&63)==0) red[t>>6]=w;
  __syncthreads();
  tot=0;
  #pragma unroll
  for(int i2=0;i2<16;i2++) tot+=red[i2];
  float var = tot*(1.0f/1024.0f);
  float y = d*rsqrtf(var+1e-5f)*lng[t] + lnb[t];
  smv[t]=y;
  __syncthreads();
  if(t<4){
    float lg=0;
    for(int j=0;j<1024;j++) lg += smv[j]*clsw[j*4+t];
    lgs[t]=lg;
  }
  __syncthreads();
  if(t==0){
    float h[4];
    int am=0; float best=lgs[0];
    #pragma unroll
    for(int c2=0;c2<4;c2++){ h[c2]=1.0f/(1.0f+expf(-lgs[c2])); if(lgs[c2]>best){best=lgs[c2];am=c2;} }
    float sv=1.0f;
    #pragma unroll
    for(int c2=0;c2<4;c2++){ out[c2]=h[c2]; sv*=(1.0f-h[c2]); out[4+c2]=sv; }
    out[8]=(float)am;
  }
}

extern "C" void kernel_launch(void* const* d_in, const int* in_sizes, int n_in,
                              void* d_out, int out_size, void* d_ws, size_t ws_size,
                              hipStream_t stream)
{
  const float* x_path =(const float*)d_in[0];
  const float* maps   =(const float*)d_in[1];
  const float* nl0_w1 =(const float*)d_in[2];
  const float* nl0_b1 =(const float*)d_in[3];
  const float* nl0_g  =(const float*)d_in[4];
  const float* nl0_bn =(const float*)d_in[5];
  const float* nl0_w2 =(const float*)d_in[6];
  const float* nl0_b2 =(const float*)d_in[7];
  const float* nl1_w1 =(const float*)d_in[8];
  const float* nl1_b1 =(const float*)d_in[9];
  const float* nl1_g  =(const float*)d_in[10];
  const float* nl1_bn =(const float*)d_in[11];
  const float* nl1_w2 =(const float*)d_in[12];
  const float* nl1_b2 =(const float*)d_in[13];
  const float *gw[6], *gb[6], *gg[6], *gbn[6];   // gc0,gc1,gc2,ga0,ga1,ga2
  for(int l=0;l<6;l++){
    gw[l]  = (const float*)d_in[14+l*4+0];
    gb[l]  = (const float*)d_in[14+l*4+1];
    gg[l]  = (const float*)d_in[14+l*4+2];
    gbn[l] = (const float*)d_in[14+l*4+3];
  }
  const float* attn_wa=(const float*)d_in[38];
  const float* attn_ba=(const float*)d_in[39];
  const float* attn_wb=(const float*)d_in[40];
  const float* attn_bb=(const float*)d_in[41];
  const float* attn_wc=(const float*)d_in[42];
  const float* attn_bc=(const float*)d_in[43];
  const float* cls_w  =(const float*)d_in[44];
  const float* ln_g   =(const float*)d_in[45];
  const float* ln_b   =(const float*)d_in[46];

  char* ws=(char*)d_ws;
  size_t off=0;
  auto alc=[&](size_t b)->char*{ char* p=ws+off; off=(off+b+255)&~(size_t)255; return p; };
  u16* BIG = (u16*)alc((size_t)N_*N_*2);          // fp8 aw, then bf16 gram (time-shared)
  u16* XB  = (u16*)alc((size_t)N_*L_*2);
  u8*  XN8 = (u8*) alc((size_t)N_*L_);
  u16* WT_proj=(u16*)alc((size_t)1536*L_*2);
  u16* WT_nl0w2=(u16*)alc((size_t)D_*D_*2);
  u16* WT_nl1w2=(u16*)alc((size_t)D_*D_*2);
  u16* WT_g[6];
  for(int l=0;l<6;l++) WT_g[l]=(u16*)alc((size_t)D_*D_*2);
  u16* SP = (u16*)alc((size_t)8*N_*D_*2);
  u16* XWT=(u16*)alc((size_t)D_*N_*2);            // bf16 XWT (gc dense fallback)
  u8*  XWT8=(u8*)alc((size_t)D_*N_);              // fp8 XWT (ga chain)
  u16* XA0=(u16*)alc((size_t)N_*D_*2);
  u16* XA1=(u16*)alc((size_t)N_*D_*2);
  u16* X0B=(u16*)alc((size_t)N_*D_*2);
  u16* X1B=(u16*)alc((size_t)N_*D_*2);
  u16* YS =(u16*)alc((size_t)N_*D_*2);
  u64* BM =(u64*)alc((size_t)N_*96*8);
  float* PART=(float*)alc((size_t)32*1024*4);
  float* AGG=(float*)alc(N_*4);
  float* SS =(float*)alc(N_*4);
  float* KI =(float*)alc(N_*4);
  float* Z  =(float*)alc(N_*4);
  float* E  =(float*)alc(N_*4);
  float* SC =(float*)alc(256);
  unsigned* MMX=(unsigned*)alc(256);
  float* SEXP=(float*)alc(256);

  const size_t PS_D = (size_t)N_*D_;
  const size_t PS_P = (size_t)N_*1536;
  u8* AW8 = (u8*)BIG;                     // fp8 aw aliases BIG (used before gram)

  init_k<<<1,1,0,stream>>>(MMX);
  hipMemsetAsync(BM, 0, (size_t)N_*96*8, stream);
  prep_x<<<N_,256,0,stream>>>(x_path, XB, XN8);

  // batched weight prep
  {
    TDescs ds;
    int base = 0;
    auto add=[&](int k, const float* s, u16* d, int R, int C){
      ds.d[k] = {s, d, R, C, base};
      base += (R>>5)*(C>>5);
    };
    add(0,  attn_wa, WT_proj,                   L_, H_);
    add(1,  attn_wb, WT_proj + (size_t)256*L_,  L_, H_);
    add(2,  nl0_w1,  WT_proj + (size_t)512*L_,  L_, D_);
    add(3,  nl1_w1,  WT_proj + (size_t)1024*L_, L_, D_);
    add(4,  nl0_w2,  WT_nl0w2, D_, D_);
    add(5,  nl1_w2,  WT_nl1w2, D_, D_);
    for(int l=0;l<6;l++) add(6+l, gw[l], WT_g[l], D_, D_);
    transpose_cast_multi<<<base,256,0,stream>>>(ds, 12);
  }

  // fused X projections: [a|b|h0|h1] = XB @ WT_proj^T  (SK=2)
  gemm_bt<<<dim3(1536/128, N_/128, 2),256,0,stream>>>(XB, WT_proj, N_, 1536, L_, SP, nullptr);
  attn_epi<<<N_/4,256,0,stream>>>(SP, PS_P, 2, attn_ba, attn_bb, attn_wc, attn_bc, AGG, SS);
  s_stats<<<1,256,0,stream>>>(SS,SC);
  aw_write<<<N_,256,0,stream>>>(maps,SS,SC,AW8);

  ln_epi_proj<<<dim3(N_/4,2),256,0,stream>>>(SP,PS_P,2,
    nl1_b1,nl1_g,nl1_bn,XA1, nl0_b1,nl0_g,nl0_bn,XA0);

  gemm_bt<<<dim3(D_/128,N_/128,4),256,0,stream>>>(XA1, WT_nl1w2, N_,D_,D_, SP, nullptr);
  bias_cast<<<(N_*D_/8)/256,256,0,stream>>>(SP,PS_D,4, nl1_b2, X1B);

  // ga chain: fp8 adjacency (aw x2048 @ xwt x4 -> descale 1/8192), SK=8
  {
    const u16* cur=X1B;
    for(int l=0;l<3;l++){
      int gi = 3+l;
      gemm_bt<<<dim3(D_/128,N_/128,4),256,0,stream>>>(cur, WT_g[gi], N_,D_,D_, SP, nullptr);
      transpose_sum_f8<<<dim3(D_/32, N_/32),256,0,stream>>>(SP, PS_D, 4, XWT8, N_, D_);
      gemm_f8<0><<<dim3(D_/128,N_/128,8),256,0,stream>>>(AW8, XWT8, N_,D_,N_, SP, nullptr);
      u16* nxt = (l==0)? XA1 : (l==1)? YS : X1B;
      ln_epi512<<<N_/4,256,0,stream>>>(SP,PS_D,8, 512,0, 1.0f/8192.0f, nullptr, gb[gi],gg[gi],gbn[gi], nxt, nullptr);
      cur = nxt;
    }
  }

  gemm_bt<<<dim3(D_/128,N_/128,4),256,0,stream>>>(XA0, WT_nl0w2, N_,D_,D_, SP, nullptr);
  bias_cast<<<(N_*D_/8)/256,256,0,stream>>>(SP,PS_D,4, nl0_b2, X0B);

  // cosine gram in fp8 (scale-invariant thresholding): balanced triangle grid
  gemm_f8<1><<<dim3(1176,1,1),256,0,stream>>>(XN8, XN8, N_,N_,L_, BIG, MMX);
  binarize_tri<<<N_,256,0,stream>>>(BIG, MMX, BM);
  binarize_fin<<<N_,256,0,stream>>>(BM, MMX, AGG, KI, Z);
  mirror_lower<<<dim3(N_/32, N_/32),256,0,stream>>>(BIG, MMX);   // dense only
  binarize_store<<<N_,256,0,stream>>>(BIG, MMX);                 // dense only

  // gc chain: sparse gather+LN fused (gated) with dense bf16 GEMM fallback
  {
    const u16* cur=X0B;
    for(int l=0;l<3;l++){
      int gi = l;
      gemm_bt<<<dim3(D_/128,N_/128,4),256,0,stream>>>(cur, WT_g[gi], N_,D_,D_, SP, nullptr);
      transpose_sum_bf<<<dim3(D_/32, N_/32),256,0,stream>>>(SP, PS_D, 4, XWT, N_, D_, MMX);
      gemm_bt<<<dim3(D_/128,N_/128,8),256,0,stream>>>(BIG, XWT, N_,D_,N_, SP, MMX);
      u16* nxt = (l==0)? XA1 : (l==1)? XA0 : X0B;
      gather_ln<<<N_,256,0,stream>>>(BM, SP, PS_D, 4, MMX, KI, gb[gi],gg[gi],gbn[gi], nxt);
      ln_epi512<<<N_/4,256,0,stream>>>(SP,PS_D,8, 512,0, 1.0f, KI, gb[gi],gg[gi],gbn[gi], nxt, MMX);
      cur = nxt;
    }
  }

  // pooling + head
  softmax_prep<<<1,1024,0,stream>>>(Z,E,SEXP);
  pooled_partial<<<32,256,0,stream>>>(E,X1B,X0B,PART);
  final_k<<<1,1024,0,stream>>>(PART,SEXP,ln_g,ln_b,cls_w,(float*)d_out);

  (void)in_sizes;(void)n_in;(void)out_size;(void)ws_size;
}

// Round 13
// 767.490 us; speedup vs baseline: 1.1102x; 1.1102x over previous
//
#include <hip/hip_runtime.h>

#define N_ 6144
#define L_ 1024
#define D_ 512
#define H_ 256
#define SPARSE_MAX 64u

typedef unsigned short u16;
typedef unsigned long long u64;
typedef __attribute__((ext_vector_type(4))) float f32x4;
typedef __attribute__((ext_vector_type(8))) short s16x8;
typedef __attribute__((ext_vector_type(4))) short s16x4;

__device__ __forceinline__ u16 f2b(float f){
  unsigned u = __float_as_uint(f);
  u += 0x7FFFu + ((u >> 16) & 1u);
  return (u16)(u >> 16);
}
__device__ __forceinline__ float b2f(u16 h){ return __uint_as_float(((unsigned)h) << 16); }
__device__ __forceinline__ unsigned fkey(float f){
  unsigned u = __float_as_uint(f);
  return (u & 0x80000000u) ? ~u : (u | 0x80000000u);
}
__device__ __forceinline__ float funkey(unsigned k){
  unsigned u = (k & 0x80000000u) ? (k & 0x7FFFFFFFu) : ~k;
  return __uint_as_float(u);
}
__device__ __forceinline__ float wave_sum(float v){
  #pragma unroll
  for(int o=32;o;o>>=1) v += __shfl_xor(v,o);
  return v;
}
__device__ __forceinline__ float wave_max(float v){
  #pragma unroll
  for(int o=32;o;o>>=1) v = fmaxf(v,__shfl_xor(v,o));
  return v;
}
__device__ __forceinline__ float wave_min(float v){
  #pragma unroll
  for(int o=32;o;o>>=1) v = fminf(v,__shfl_xor(v,o));
  return v;
}
__device__ __forceinline__ float blk_sum256(float v){
  __shared__ float sm[4];
  v = wave_sum(v);
  __syncthreads();
  if((threadIdx.x&63)==0) sm[threadIdx.x>>6]=v;
  __syncthreads();
  return sm[0]+sm[1]+sm[2]+sm[3];
}
__device__ __forceinline__ float blk_min256(float v){
  __shared__ float sm[4];
  v = wave_min(v);
  __syncthreads();
  if((threadIdx.x&63)==0) sm[threadIdx.x>>6]=v;
  __syncthreads();
  return fminf(fminf(sm[0],sm[1]),fminf(sm[2],sm[3]));
}
__device__ __forceinline__ float blk_max256(float v){
  __shared__ float sm[4];
  v = wave_max(v);
  __syncthreads();
  if((threadIdx.x&63)==0) sm[threadIdx.x>>6]=v;
  __syncthreads();
  return fmaxf(fmaxf(sm[0],sm[1]),fmaxf(sm[2],sm[3]));
}

// ---------------- 128x128 GEMM: C[M,Nc] = A @ Bt^T (bf16) ------------------
// 3-buffer staging, XCD-chunked swizzle, LDS-bounce epilogue, split-K planes.
// MODE 0: write bf16 plane z.  gate!=null && sparse -> early exit.
// MODE 1 (gram): BALANCED upper-triangle 1-D grid (1176 blocks, bijective
//                lid->(i<=j) map, XCD-chunked) + NT store + min/max atomics.
template<int VW> __device__ __forceinline__ void waitv(){
  if constexpr(VW==8) asm volatile("s_waitcnt vmcnt(8)" ::: "memory");
  else if constexpr(VW==4) asm volatile("s_waitcnt vmcnt(4)" ::: "memory");
  else asm volatile("s_waitcnt vmcnt(0)" ::: "memory");
}

#define STG4(bb,k0) do{ \
  __builtin_amdgcn_global_load_lds((__attribute__((address_space(1))) void*)(gA0+(k0)), (__attribute__((address_space(3))) void*)(lds + (bb)*4096 + (wid<<9)),        16, 0, 0); \
  __builtin_amdgcn_global_load_lds((__attribute__((address_space(1))) void*)(gA1+(k0)), (__attribute__((address_space(3))) void*)(lds + (bb)*4096 + 2048 + (wid<<9)), 16, 0, 0); \
  __builtin_amdgcn_global_load_lds((__attribute__((address_space(1))) void*)(gB0+(k0)), (__attribute__((address_space(3))) void*)(lds + 12288 + (bb)*4096 + (wid<<9)),        16, 0, 0); \
  __builtin_amdgcn_global_load_lds((__attribute__((address_space(1))) void*)(gB1+(k0)), (__attribute__((address_space(3))) void*)(lds + 12288 + (bb)*4096 + 2048 + (wid<<9)), 16, 0, 0); \
}while(0)

template<int MODE>
__global__ __launch_bounds__(256) void gemm_bt(
  const u16* __restrict__ A, const u16* __restrict__ Bt,
  int M, int Nc, int K,
  u16* __restrict__ Cb, unsigned* __restrict__ mmx,
  const unsigned* __restrict__ gate)
{
  if (gate && gate[2] <= SPARSE_MAX) return;
  __shared__ __align__(16) u16 lds[3*4096*2];   // 48 KB
  const int tid = threadIdx.x;
  const int wid = tid>>6, lane = tid&63;

  int m0, n0;
  if (MODE==1){
    // balanced upper-triangle map: 1176 blocks, XCD-chunked (1176 = 8*147)
    int t = (int)blockIdx.x;
    t = (t&7)*147 + (t>>3);
    int i=0, rem=t;
    while (rem >= 48-i){ rem -= 48-i; ++i; }
    m0 = i<<7; n0 = (i+rem)<<7;
  } else {
    const int gx = gridDim.x;
    int lid = blockIdx.y*gx + blockIdx.x;
    const int nwg = gx*gridDim.y;
    if ((nwg & 7) == 0) {
      const int chunk = nwg >> 3;
      lid = (lid & 7)*chunk + (lid >> 3);
    }
    m0 = (lid/gx)<<7; n0 = (lid%gx)<<7;
  }
  const int wr = wid>>1, wc = wid&1;

  const int Klen = K / gridDim.z;
  const int kbeg = blockIdx.z * Klen;

  const int srow = (wid<<4) + (lane>>2);
  const int scol = (lane&3)<<3;
  const u16* gA0 = A  + (size_t)(m0+srow   )*K + scol;
  const u16* gA1 = A  + (size_t)(m0+srow+64)*K + scol;
  const u16* gB0 = Bt + (size_t)(n0+srow   )*K + scol;
  const u16* gB1 = Bt + (size_t)(n0+srow+64)*K + scol;

  f32x4 acc[4][4] = {};
  const int lr = lane&15, lk = (lane>>4)<<3;

  const int NIT = Klen>>5;   // >= 3 required (all launches satisfy)
  STG4(0, kbeg);
  STG4(1, kbeg+32);
  STG4(2, kbeg+64);

  for (int it=0; it<NIT-2; ++it){
    const int b = it - (it/3)*3;
    waitv<8>();
    __builtin_amdgcn_s_barrier();
    const u16* baseA = lds + b*4096;
    const u16* baseB = lds + 12288 + b*4096;
    s16x8 af[4], bfr[4];
    #pragma unroll
    for(int m=0;m<4;m++) af[m]  = *(const s16x8*)(baseA + ((wr<<6)+(m<<4)+lr)*32 + lk);
    #pragma unroll
    for(int n=0;n<4;n++) bfr[n] = *(const s16x8*)(baseB + ((wc<<6)+(n<<4)+lr)*32 + lk);
    asm volatile("s_waitcnt lgkmcnt(0)" ::: "memory");
    __builtin_amdgcn_sched_barrier(0);
    __builtin_amdgcn_s_barrier();
    if (it+3 < NIT) STG4(b, kbeg + ((it+3)<<5));
    #pragma unroll
    for(int m=0;m<4;m++)
      #pragma unroll
      for(int n=0;n<4;n++)
        acc[m][n] = __builtin_amdgcn_mfma_f32_16x16x32_bf16(af[m], bfr[n], acc[m][n], 0,0,0);
  }
  {
    const int it = NIT-2; const int b = it - (it/3)*3;
    waitv<4>();
    __builtin_amdgcn_s_barrier();
    const u16* baseA = lds + b*4096;
    const u16* baseB = lds + 12288 + b*4096;
    s16x8 af[4], bfr[4];
    #pragma unroll
    for(int m=0;m<4;m++) af[m]  = *(const s16x8*)(baseA + ((wr<<6)+(m<<4)+lr)*32 + lk);
    #pragma unroll
    for(int n=0;n<4;n++) bfr[n] = *(const s16x8*)(baseB + ((wc<<6)+(n<<4)+lr)*32 + lk);
    #pragma unroll
    for(int m=0;m<4;m++)
      #pragma unroll
      for(int n=0;n<4;n++)
        acc[m][n] = __builtin_amdgcn_mfma_f32_16x16x32_bf16(af[m], bfr[n], acc[m][n], 0,0,0);
  }
  {
    const int it = NIT-1; const int b = it - (it/3)*3;
    waitv<0>();
    __builtin_amdgcn_s_barrier();
    const u16* baseA = lds + b*4096;
    const u16* baseB = lds + 12288 + b*4096;
    s16x8 af[4], bfr[4];
    #pragma unroll
    for(int m=0;m<4;m++) af[m]  = *(const s16x8*)(baseA + ((wr<<6)+(m<<4)+lr)*32 + lk);
    #pragma unroll
    for(int n=0;n<4;n++) bfr[n] = *(const s16x8*)(baseB + ((wc<<6)+(n<<4)+lr)*32 + lk);
    #pragma unroll
    for(int m=0;m<4;m++)
      #pragma unroll
      for(int n=0;n<4;n++)
        acc[m][n] = __builtin_amdgcn_mfma_f32_16x16x32_bf16(af[m], bfr[n], acc[m][n], 0,0,0);
  }

  // MODE 1: min/max from registers (before LDS reuse)
  float tmin = 3.0e38f, tmax = -3.0e38f;
  if (MODE==1){
    #pragma unroll
    for(int m=0;m<4;m++)
      #pragma unroll
      for(int n=0;n<4;n++){
        f32x4 v = acc[m][n];
        #pragma unroll
        for(int e=0;e<4;e++){ tmin = fminf(tmin,v[e]); tmax = fmaxf(tmax,v[e]); }
      }
  }

  __syncthreads();
  u16* lC = lds;
  {
    const int rb_l = (wr<<6) + ((lane>>4)<<2);
    const int cb_l = (wc<<6) + lr;
    #pragma unroll
    for(int m=0;m<4;m++)
      #pragma unroll
      for(int n=0;n<4;n++){
        f32x4 v = acc[m][n];
        #pragma unroll
        for(int e=0;e<4;e++)
          lC[(rb_l+(m<<4)+e)*128 + cb_l+(n<<4)] = f2b(v[e]);
      }
  }
  __syncthreads();
  u16* Cp = (MODE==0) ? (Cb + (size_t)blockIdx.z * M * Nc) : Cb;
  #pragma unroll
  for(int q=0;q<8;q++){
    int c = (q<<8) + tid;
    int r = c>>4, cc = (c&15)<<3;
    s16x8 v = *(const s16x8*)(lC + r*128 + cc);
    if (MODE==1)
      __builtin_nontemporal_store(v, (s16x8*)(Cp + (size_t)(m0+r)*Nc + n0 + cc));
    else
      *(s16x8*)(Cp + (size_t)(m0+r)*Nc + n0 + cc) = v;
  }

  if (MODE==1){
    tmin = wave_min(tmin); tmax = wave_max(tmax);
    __shared__ float rmn[4], rmx[4];
    if(lane==0){ rmn[wid]=tmin; rmx[wid]=tmax; }
    __syncthreads();
    if(tid==0){
      float mn=fminf(fminf(rmn[0],rmn[1]),fminf(rmn[2],rmn[3]));
      float mx=fmaxf(fmaxf(rmx[0],rmx[1]),fmaxf(rmx[2],rmx[3]));
      atomicMin(mmx+0, fkey(mn));
      atomicMax(mmx+1, fkey(mx));
    }
  }
}

// DENSE-FALLBACK ONLY: copy strictly-upper 128-blocks of C to lower, transposed
__global__ __launch_bounds__(256) void mirror_lower(u16* __restrict__ C,
  const unsigned* __restrict__ gate)
{
  if (gate[2] <= SPARSE_MAX) return;
  int c0 = blockIdx.x<<5, r0 = blockIdx.y<<5;   // source tile (upper)
  if ((r0>>7) >= (c0>>7)) return;               // only strictly-upper 128-blocks
  __shared__ u16 t[32][33];
  int tx = threadIdx.x&31, ty = threadIdx.x>>5;
  #pragma unroll
  for(int i=0;i<32;i+=8) t[ty+i][tx] = C[(size_t)(r0+ty+i)*N_ + c0+tx];
  __syncthreads();
  #pragma unroll
  for(int i=0;i<32;i+=8)
    __builtin_nontemporal_store(t[tx][ty+i], C + (size_t)(c0+ty+i)*N_ + r0+tx);
}

// batched weight-prep transposes: fp32 [R][C] -> bf16 [C][R], 12 descriptors
struct TDesc { const float* src; u16* dst; int R; int C; int base; };
struct TDescs { TDesc d[12]; };
__global__ __launch_bounds__(256) void transpose_cast_multi(TDescs ds, int nd)
{
  int b = (int)blockIdx.x;
  int k = 0;
  for (int q=1;q<nd;q++) if (b >= ds.d[q].base) k = q;
  const float* src = ds.d[k].src;
  u16* dst = ds.d[k].dst;
  int R = ds.d[k].R, C = ds.d[k].C;
  int lt = b - ds.d[k].base;
  int tc = C>>5;
  int bx = lt % tc, by = lt / tc;
  __shared__ float t[32][33];
  int c0 = bx<<5, r0 = by<<5;
  int tx = threadIdx.x&31, ty = threadIdx.x>>5;
  #pragma unroll
  for(int i=0;i<32;i+=8) t[ty+i][tx] = src[(size_t)(r0+ty+i)*C + c0+tx];
  __syncthreads();
  #pragma unroll
  for(int i=0;i<32;i+=8) dst[(size_t)(c0+ty+i)*R + r0+tx] = f2b(t[tx][ty+i]);
}

// dst[C][R] bf16 = transpose( sum_p bf16_plane_p [R][C] ); gated (dense path)
__global__ __launch_bounds__(256) void transpose_sum_bf(
  const u16* __restrict__ src, size_t pstr, int nsp,
  u16* __restrict__ dst, int R, int C, const unsigned* __restrict__ gate)
{
  if (gate && gate[2] <= SPARSE_MAX) return;
  __shared__ float t[32][33];
  int c0 = blockIdx.x<<5, r0 = blockIdx.y<<5;
  int tx = threadIdx.x&31, ty = threadIdx.x>>5;
  #pragma unroll
  for(int i=0;i<32;i+=8){
    float v = 0;
    for(int p=0;p<nsp;p++)
      v += b2f(src[(size_t)p*pstr + (size_t)(r0+ty+i)*C + c0+tx]);
    t[ty+i][tx] = v;
  }
  __syncthreads();
  #pragma unroll
  for(int i=0;i<32;i+=8) dst[(size_t)(c0+ty+i)*R + r0+tx] = f2b(t[tx][ty+i]);
}

__global__ __launch_bounds__(256) void prep_x(const float* __restrict__ x,
  u16* __restrict__ xb, u16* __restrict__ xnb)
{
  int row = blockIdx.x, t = threadIdx.x;
  const float* p = x + (size_t)row*L_ + (t<<2);
  f32x4 v = *(const f32x4*)p;
  float ss = v[0]*v[0]+v[1]*v[1]+v[2]*v[2]+v[3]*v[3];
  float tot = blk_sum256(ss);
  float inv = 1.0f/fmaxf(sqrtf(tot), 1e-12f);
  u16* pb = xb  + (size_t)row*L_ + (t<<2);
  u16* pn = xnb + (size_t)row*L_ + (t<<2);
  #pragma unroll
  for(int k=0;k<4;k++){ pb[k]=f2b(v[k]); pn[k]=f2b(v[k]*inv); }
}

// fused-projection epilogue: a at cols [0,256), b at [256,512) of [N,1536] planes
__global__ __launch_bounds__(256) void attn_epi(const u16* __restrict__ SPA,
  size_t pstr, int nsp,
  const float* __restrict__ ba, const float* __restrict__ bb,
  const float* __restrict__ wc, const float* __restrict__ bc,
  float* __restrict__ agg, float* __restrict__ s)
{
  int row = (blockIdx.x<<2) + (threadIdx.x>>6);
  int lane = threadIdx.x&63;
  float a[4]={0,0,0,0}, b[4]={0,0,0,0};
  for(int p=0;p<nsp;p++){
    s16x4 ua = *(const s16x4*)(SPA + (size_t)p*pstr + (size_t)row*1536 + (lane<<2));
    s16x4 ub = *(const s16x4*)(SPA + (size_t)p*pstr + (size_t)row*1536 + 256 + (lane<<2));
    #pragma unroll
    for(int j=0;j<4;j++){ a[j]+=b2f((u16)ua[j]); b[j]+=b2f((u16)ub[j]); }
  }
  float acc=0;
  #pragma unroll
  for(int j=0;j<4;j++){
    int h = (lane<<2)+j;
    float tv = tanhf(a[j]+ba[h]);
    float sg = 1.0f/(1.0f+expf(-(b[j]+bb[h])));
    acc += tv*sg*wc[h];
  }
  acc = wave_sum(acc);
  if(lane==0){
    float v = acc + bc[0];
    agg[row]=v;
    s[row]=1.0f/(1.0f+expf(-v));
  }
}

// single-block min/max of s (no global atomic contention)
__global__ __launch_bounds__(256) void s_stats(const float* __restrict__ s, float* __restrict__ sc){
  int t=threadIdx.x;
  float mn=3e38f, mx=-3e38f;
  for(int i=t;i<N_;i+=256){ float v=s[i]; mn=fminf(mn,v); mx=fmaxf(mx,v); }
  float MN=blk_min256(mn);
  float MX=blk_max256(mx);
  if(t==0){ sc[0]=MN; sc[1]=MX; }
}

__global__ __launch_bounds__(256) void aw_write(const float* __restrict__ maps, const float* __restrict__ s,
  const float* __restrict__ sc, u16* __restrict__ awb)
{
  int i = blockIdx.x, t = threadIdx.x;
  float smin = sc[0], smax = sc[1];
  float mn = smin*smin, mx = smax*smax;
  float beta = 0.6f/(mx-mn);
  float c1 = 0.4f - beta*mn;
  float si = s[i];
  const float* mrow = maps + (size_t)i*N_;
  float mv[24];
  float part = 0;
  #pragma unroll
  for(int q=0;q<24;q++){
    int j = t + (q<<8);
    mv[q] = c1 + beta*si*s[j] + mrow[j];
    part += mv[q];
  }
  float r = blk_sum256(part);
  float inv = 1.0f/fmaxf(r, 1e-12f);
  u16* orow = awb + (size_t)i*N_;
  #pragma unroll
  for(int q=0;q<24;q++)
    __builtin_nontemporal_store(f2b(mv[q]*inv), orow + t + (q<<8));
}

// out = relu(LN( (sum_p Y_p)*rowscale + bias )).  Dense path only.
__global__ __launch_bounds__(256) void ln_epi512(const u16* __restrict__ Y, size_t pstr, int nsp,
  int rs, int cbase,
  const float* __restrict__ ki,
  const float* __restrict__ bias, const float* __restrict__ g, const float* __restrict__ bn,
  u16* __restrict__ outb,
  const unsigned* __restrict__ gate)
{
  if (gate && gate[2] <= SPARSE_MAX) return;
  int row = (blockIdx.x<<2)+(threadIdx.x>>6);
  int lane = threadIdx.x&63;
  int c0 = lane<<3;
  float v[8] = {0,0,0,0,0,0,0,0};
  for(int p=0;p<nsp;p++){
    s16x8 u = *(const s16x8*)(Y + (size_t)p*pstr + (size_t)row*rs + cbase + c0);
    #pragma unroll
    for(int j=0;j<8;j++) v[j] += b2f((u16)u[j]);
  }
  float scale = ki ? (1.0f/ki[row]) : 1.0f;
  float sum=0, ssum=0;
  #pragma unroll
  for(int j=0;j<8;j++){ v[j] = v[j]*scale + bias[c0+j]; sum+=v[j]; ssum+=v[j]*v[j]; }
  sum = wave_sum(sum); ssum = wave_sum(ssum);
  float m = sum*(1.0f/D_);
  float var = ssum*(1.0f/D_) - m*m;
  float invsd = rsqrtf(var + 1e-5f);
  u16 ob[8];
  #pragma unroll
  for(int j=0;j<8;j++){
    float o = (v[j]-m)*invsd*g[c0+j] + bn[c0+j];
    o = fmaxf(o, 0.0f);
    ob[j] = f2b(o);
  }
  *(s16x8*)(outb + (size_t)row*D_ + c0) = *(s16x8*)ob;
}

// both proj LNs in one launch: blockIdx.y==0 -> nl1 (cbase 1024), ==1 -> nl0 (512)
__global__ __launch_bounds__(256) void ln_epi_proj(const u16* __restrict__ Y, size_t pstr, int nsp,
  const float* __restrict__ b1, const float* __restrict__ g1, const float* __restrict__ n1, u16* __restrict__ o1,
  const float* __restrict__ b0, const float* __restrict__ g0, const float* __restrict__ n0, u16* __restrict__ o0)
{
  const int sel = blockIdx.y;
  const int cbase = sel ? 512 : 1024;
  const float* bias = sel ? b0 : b1;
  const float* g    = sel ? g0 : g1;
  const float* bn   = sel ? n0 : n1;
  u16* outb         = sel ? o0 : o1;
  int row = (blockIdx.x<<2)+(threadIdx.x>>6);
  int lane = threadIdx.x&63;
  int c0 = lane<<3;
  float v[8] = {0,0,0,0,0,0,0,0};
  for(int p=0;p<nsp;p++){
    s16x8 u = *(const s16x8*)(Y + (size_t)p*pstr + (size_t)row*1536 + cbase + c0);
    #pragma unroll
    for(int j=0;j<8;j++) v[j] += b2f((u16)u[j]);
  }
  float sum=0, ssum=0;
  #pragma unroll
  for(int j=0;j<8;j++){ v[j] = v[j] + bias[c0+j]; sum+=v[j]; ssum+=v[j]*v[j]; }
  sum = wave_sum(sum); ssum = wave_sum(ssum);
  float m = sum*(1.0f/D_);
  float var = ssum*(1.0f/D_) - m*m;
  float invsd = rsqrtf(var + 1e-5f);
  u16 ob[8];
  #pragma unroll
  for(int j=0;j<8;j++){
    float o = (v[j]-m)*invsd*g[c0+j] + bn[c0+j];
    o = fmaxf(o, 0.0f);
    ob[j] = f2b(o);
  }
  *(s16x8*)(outb + (size_t)row*D_ + c0) = *(s16x8*)ob;
}

__global__ __launch_bounds__(256) void bias_cast(const u16* __restrict__ Y, size_t pstr, int nsp,
  const float* __restrict__ b, u16* __restrict__ outb)
{
  size_t idx = ((size_t)blockIdx.x*256 + threadIdx.x)<<3;
  float v[8] = {0,0,0,0,0,0,0,0};
  for(int p=0;p<nsp;p++){
    s16x8 u = *(const s16x8*)(Y + (size_t)p*pstr + idx);
    #pragma unroll
    for(int j=0;j<8;j++) v[j] += b2f((u16)u[j]);
  }
  int c = (int)(idx & (D_-1));
  u16 ob[8];
  #pragma unroll
  for(int k=0;k<8;k++) ob[k] = f2b(v[k]+b[c+k]);
  *(s16x8*)(outb+idx) = *(s16x8*)ob;
}

__global__ void init_k(unsigned* mmx){
  mmx[0]=0xFFFFFFFFu; mmx[1]=0u; mmx[2]=0u;   // gram min/max, max-nnz (0 = sparse)
}

// upper-triangle binarize: scans only j>=i of the gram (lower half is stale).
// Writes bitmap: words > boundary via plain store; boundary word and rare
// mirrored bits (j>i) via atomicOr (idempotent -> deterministic). BM pre-zeroed.
__global__ __launch_bounds__(256) void binarize_tri(const u16* __restrict__ csb,
  const unsigned* __restrict__ mmx, u64* __restrict__ bm)
{
  int i = blockIdx.x, t = threadIdx.x;
  int lane = t&63, w = t>>6;
  float mn = funkey(mmx[0]), mx = funkey(mmx[1]);
  float th = mn + 0.5f*(mx-mn);
  const u16* row = csb + (size_t)i*N_;
  u64* bmrow = bm + (size_t)i*96;
  const int w0 = i>>6;                   // boundary word
  for (int wq = w0 + w; wq < 96; wq += 4){
    int j = (wq<<6) + lane;
    bool on = (j >= i) && (b2f(row[j]) >= th);
    u64 mask = __ballot(on);
    if (lane == 0){
      if (wq == w0) atomicOr((u64*)(bmrow+wq), mask);
      else bmrow[wq] = mask;
    }
    if (on && j > i)
      atomicOr((u64*)(bm + (size_t)j*96 + w0), 1ull << (i&63));
  }
}

// finalize from completed bitmap: ki, z, max-nnz (deterministic: fixed order)
__global__ __launch_bounds__(256) void binarize_fin(const u64* __restrict__ bm,
  unsigned* __restrict__ mmx, const float* __restrict__ agg,
  float* __restrict__ ki, float* __restrict__ z)
{
  int i = blockIdx.x, t = threadIdx.x;
  float cnt = 0, dot = 0;
  if (t < 96){
    u64 m = bm[(size_t)i*96 + t];
    cnt = (float)__popcll(m);
    while (m){
      int b = __ffsll((long long)m) - 1;
      m &= m - 1;
      dot += agg[(t<<6) + b];
    }
  }
  float k  = blk_sum256(cnt);
  float dt = blk_sum256(dot);
  if (t==0){
    ki[i] = k;
    float tr = dt/(k*sqrtf((float)N_));
    z[i] = 0.3f*tr + 0.7f*agg[i];
    if (k > (float)SPARSE_MAX)
      atomicMax(mmx+2, (unsigned)(k+0.5f));
  }
}

// dense-fallback only: rewrite BIG in place as 0/1 bf16 (after mirror_lower)
__global__ __launch_bounds__(256) void binarize_store(u16* __restrict__ csb,
  const unsigned* __restrict__ mmx)
{
  if (mmx[2] <= SPARSE_MAX) return;
  int i = blockIdx.x, t = threadIdx.x;
  float mn = funkey(mmx[0]), mx = funkey(mmx[1]);
  float th = mn + 0.5f*(mx-mn);
  u16* row = csb + (size_t)i*N_;
  #pragma unroll
  for(int q=0;q<24;q++){
    int j = t + (q<<8);
    row[j] = (b2f(row[j]) >= th) ? (u16)0x3F80 : (u16)0;
  }
}

// sparse adjacency apply FUSED with LN epilogue:
// row i: y = sum_{j: bit} sum_p SP[p][j,:]; out = relu(LN(y/ki + bias))
__global__ __launch_bounds__(256) void gather_ln(const u64* __restrict__ bm,
  const u16* __restrict__ SPp, size_t pstr, int nsp,
  const unsigned* __restrict__ gate, const float* __restrict__ ki,
  const float* __restrict__ bias, const float* __restrict__ g, const float* __restrict__ bn,
  u16* __restrict__ outb)
{
  if (gate[2] > SPARSE_MAX) return;
  int i = blockIdx.x, t = threadIdx.x;
  __shared__ u64 wbuf[96];
  __shared__ u16 idx[SPARSE_MAX];
  __shared__ int nn_s;
  if (t < 96) wbuf[t] = bm[(size_t)i*96 + t];
  __syncthreads();
  if (t == 0){
    int nn = 0;
    for(int k=0;k<96;k++){
      u64 m = wbuf[k];
      while(m && nn < (int)SPARSE_MAX){
        int b = __ffsll((long long)m) - 1;
        m &= m - 1;
        idx[nn++] = (u16)((k<<6) + b);
      }
    }
    nn_s = nn;
  }
  __syncthreads();
  int nn = nn_s;
  float a0=0, a1=0;
  for(int k=0;k<nn;k++){
    size_t jb = (size_t)idx[k]*512;
    for(int p=0;p<nsp;p++){
      a0 += b2f(SPp[p*pstr + jb + t]);
      a1 += b2f(SPp[p*pstr + jb + t + 256]);
    }
  }
  float scale = 1.0f/ki[i];
  float v0 = a0*scale + bias[t];
  float v1 = a1*scale + bias[t+256];
  float sum  = blk_sum256(v0+v1);
  float ssum = blk_sum256(v0*v0+v1*v1);
  float m = sum*(1.0f/512.0f);
  float var = ssum*(1.0f/512.0f) - m*m;
  float inv = rsqrtf(var+1e-5f);
  float o0 = fmaxf((v0-m)*inv*g[t]+bn[t], 0.0f);
  float o1 = fmaxf((v1-m)*inv*g[t+256]+bn[t+256], 0.0f);
  outb[(size_t)i*512 + t]       = f2b(o0);
  outb[(size_t)i*512 + t + 256] = f2b(o1);
}

__global__ __launch_bounds__(1024) void softmax_prep(const float* __restrict__ z,
  float* __restrict__ e, float* __restrict__ sexp)
{
  int t = threadIdx.x;
  __shared__ float sm[16];
  float mx=-3e38f;
  for(int i=t;i<N_;i+=1024) mx=fmaxf(mx,z[i]);
  mx = wave_max(mx);
  if((t&63)==0) sm[t>>6]=mx;
  __syncthreads();
  float zm = sm[0];
  #pragma unroll
  for(int w=1;w<16;w++) zm=fmaxf(zm,sm[w]);
  __syncthreads();
  float sum=0;
  for(int i=t;i<N_;i+=1024){ float ee=expf(z[i]-zm); e[i]=ee; sum+=ee; }
  sum = wave_sum(sum);
  if((t&63)==0) sm[t>>6]=sum;
  __syncthreads();
  if(t==0){ float S=0; for(int w=0;w<16;w++) S+=sm[w]; *sexp=S; }
}

// pooled partial sums over 192 rows/block; g2/g1 are bf16 [N,512]
__global__ __launch_bounds__(256) void pooled_partial(const float* __restrict__ e,
  const u16* __restrict__ g2b, const u16* __restrict__ g1b, float* __restrict__ part)
{
  int b = blockIdx.x, t = threadIdx.x;
  float a0=0,a1=0,a2=0,a3=0;
  for(int r=0;r<192;r++){
    int row = b*192+r;
    float w = e[row];
    a0 += w * b2f(g2b[(size_t)row*D_ + t]);
    a1 += w * b2f(g2b[(size_t)row*D_ + t+256]);
    a2 += w * b2f(g1b[(size_t)row*D_ + t]);
    a3 += w * b2f(g1b[(size_t)row*D_ + t+256]);
  }
  part[(size_t)b*1024 + t]      = a0;
  part[(size_t)b*1024 + t+256]  = a1;
  part[(size_t)b*1024 + t+512]  = a2;
  part[(size_t)b*1024 + t+768]  = a3;
}

__global__ __launch_bounds__(1024) void final_k(const float* __restrict__ part, const float* __restrict__ sexp,
  const float* __restrict__ lng, const float* __restrict__ lnb,
  const float* __restrict__ clsw, float* __restrict__ out)
{
  int t = threadIdx.x;
  __shared__ float red[16];
  __shared__ float smv[1024];
  __shared__ float lgs[4];
  float p=0;
  for(int b=0;b<32;b++) p += part[b*1024 + t];
  p /= sexp[0];
  float w = wave_sum(p);
  if((t&63)==0) red[t>>6]=w;
  __syncthreads();
  float tot=0;
  #pragma unroll
  for(int i2=0;i2<16;i2++) tot+=red[i2];
  float m = tot*(1.0f/1024.0f);
  __syncthreads();
  float d = p-m;
  w = wave_sum(d*d);
  if((t&63)==0) red[t>>6]=w;
  __syncthreads();
  tot=0;
  #pragma unroll
  for(int i2=0;i2<16;i2++) tot+=red[i2];
  float var = tot*(1.0f/1024.0f);
  float y = d*rsqrtf(var+1e-5f)*lng[t] + lnb[t];
  smv[t]=y;
  __syncthreads();
  if(t<4){
    float lg=0;
    for(int j=0;j<1024;j++) lg += smv[j]*clsw[j*4+t];
    lgs[t]=lg;
  }
  __syncthreads();
  if(t==0){
    float h[4];
    int am=0; float best=lgs[0];
    #pragma unroll
    for(int c2=0;c2<4;c2++){ h[c2]=1.0f/(1.0f+expf(-lgs[c2])); if(lgs[c2]>best){best=lgs[c2];am=c2;} }
    float sv=1.0f;
    #pragma unroll
    for(int c2=0;c2<4;c2++){ out[c2]=h[c2]; sv*=(1.0f-h[c2]); out[4+c2]=sv; }
    out[8]=(float)am;
  }
}

extern "C" void kernel_launch(void* const* d_in, const int* in_sizes, int n_in,
                              void* d_out, int out_size, void* d_ws, size_t ws_size,
                              hipStream_t stream)
{
  const float* x_path =(const float*)d_in[0];
  const float* maps   =(const float*)d_in[1];
  const float* nl0_w1 =(const float*)d_in[2];
  const float* nl0_b1 =(const float*)d_in[3];
  const float* nl0_g  =(const float*)d_in[4];
  const float* nl0_bn =(const float*)d_in[5];
  const float* nl0_w2 =(const float*)d_in[6];
  const float* nl0_b2 =(const float*)d_in[7];
  const float* nl1_w1 =(const float*)d_in[8];
  const float* nl1_b1 =(const float*)d_in[9];
  const float* nl1_g  =(const float*)d_in[10];
  const float* nl1_bn =(const float*)d_in[11];
  const float* nl1_w2 =(const float*)d_in[12];
  const float* nl1_b2 =(const float*)d_in[13];
  const float *gw[6], *gb[6], *gg[6], *gbn[6];   // gc0,gc1,gc2,ga0,ga1,ga2
  for(int l=0;l<6;l++){
    gw[l]  = (const float*)d_in[14+l*4+0];
    gb[l]  = (const float*)d_in[14+l*4+1];
    gg[l]  = (const float*)d_in[14+l*4+2];
    gbn[l] = (const float*)d_in[14+l*4+3];
  }
  const float* attn_wa=(const float*)d_in[38];
  const float* attn_ba=(const float*)d_in[39];
  const float* attn_wb=(const float*)d_in[40];
  const float* attn_bb=(const float*)d_in[41];
  const float* attn_wc=(const float*)d_in[42];
  const float* attn_bc=(const float*)d_in[43];
  const float* cls_w  =(const float*)d_in[44];
  const float* ln_g   =(const float*)d_in[45];
  const float* ln_b   =(const float*)d_in[46];

  char* ws=(char*)d_ws;
  size_t off=0;
  auto alc=[&](size_t b)->char*{ char* p=ws+off; off=(off+b+255)&~(size_t)255; return p; };
  u16* BIG = (u16*)alc((size_t)N_*N_*2);          // aw, then cs gram (time-shared)
  u16* XB  = (u16*)alc((size_t)N_*L_*2);
  u16* XNB = (u16*)alc((size_t)N_*L_*2);
  u16* WT_proj=(u16*)alc((size_t)1536*L_*2);      // [wa;wb;nl0w1;nl1w1] transposed
  u16* WT_nl0w2=(u16*)alc((size_t)D_*D_*2);
  u16* WT_nl1w2=(u16*)alc((size_t)D_*D_*2);
  u16* WT_g[6];
  for(int l=0;l<6;l++) WT_g[l]=(u16*)alc((size_t)D_*D_*2);
  u16* SP = (u16*)alc((size_t)8*N_*D_*2);         // planes: proj SK2 or 8x[N,512]
  u16* XWT=(u16*)alc((size_t)D_*N_*2);
  u16* XA0=(u16*)alc((size_t)N_*D_*2);
  u16* XA1=(u16*)alc((size_t)N_*D_*2);
  u16* X0B=(u16*)alc((size_t)N_*D_*2);
  u16* X1B=(u16*)alc((size_t)N_*D_*2);
  u16* YS =(u16*)alc((size_t)N_*D_*2);
  u64* BM =(u64*)alc((size_t)N_*96*8);
  float* PART=(float*)alc((size_t)32*1024*4);
  float* AGG=(float*)alc(N_*4);
  float* SS =(float*)alc(N_*4);
  float* KI =(float*)alc(N_*4);
  float* Z  =(float*)alc(N_*4);
  float* E  =(float*)alc(N_*4);
  float* SC =(float*)alc(256);
  unsigned* MMX=(unsigned*)alc(256);
  float* SEXP=(float*)alc(256);

  const size_t PS_D = (size_t)N_*D_;      // 512-col plane stride
  const size_t PS_P = (size_t)N_*1536;    // proj plane stride

  init_k<<<1,1,0,stream>>>(MMX);
  hipMemsetAsync(BM, 0, (size_t)N_*96*8, stream);
  prep_x<<<N_,256,0,stream>>>(x_path, XB, XNB);

  // batched weight prep (12 transposes in one launch)
  {
    TDescs ds;
    int base = 0;
    auto add=[&](int k, const float* s, u16* d, int R, int C){
      ds.d[k] = {s, d, R, C, base};
      base += (R>>5)*(C>>5);
    };
    add(0,  attn_wa, WT_proj,                   L_, H_);
    add(1,  attn_wb, WT_proj + (size_t)256*L_,  L_, H_);
    add(2,  nl0_w1,  WT_proj + (size_t)512*L_,  L_, D_);
    add(3,  nl1_w1,  WT_proj + (size_t)1024*L_, L_, D_);
    add(4,  nl0_w2,  WT_nl0w2, D_, D_);
    add(5,  nl1_w2,  WT_nl1w2, D_, D_);
    for(int l=0;l<6;l++) add(6+l, gw[l], WT_g[l], D_, D_);
    transpose_cast_multi<<<base,256,0,stream>>>(ds, 12);
  }

  // fused X projections: [a|b|h0|h1] = XB @ WT_proj^T  (SK=2)
  gemm_bt<0><<<dim3(1536/128, N_/128, 2),256,0,stream>>>(XB, WT_proj, N_, 1536, L_, SP, nullptr, nullptr);
  attn_epi<<<N_/4,256,0,stream>>>(SP, PS_P, 2, attn_ba, attn_bb, attn_wc, attn_bc, AGG, SS);
  s_stats<<<1,256,0,stream>>>(SS,SC);
  aw_write<<<N_,256,0,stream>>>(maps,SS,SC,BIG);

  // both proj LNs in one launch
  ln_epi_proj<<<dim3(N_/4,2),256,0,stream>>>(SP,PS_P,2,
    nl1_b1,nl1_g,nl1_bn,XA1, nl0_b1,nl0_g,nl0_bn,XA0);

  gemm_bt<0><<<dim3(D_/128,N_/128,4),256,0,stream>>>(XA1, WT_nl1w2, N_,D_,D_, SP, nullptr, nullptr);
  bias_cast<<<(N_*D_/8)/256,256,0,stream>>>(SP,PS_D,4, nl1_b2, X1B);

  // ga chain (dense adjacency = BIG = aw); adjacency GEMM split-K=8
  {
    const u16* cur=X1B;
    for(int l=0;l<3;l++){
      int gi = 3+l;
      gemm_bt<0><<<dim3(D_/128,N_/128,4),256,0,stream>>>(cur, WT_g[gi], N_,D_,D_, SP, nullptr, nullptr);
      transpose_sum_bf<<<dim3(D_/32, N_/32),256,0,stream>>>(SP, PS_D, 4, XWT, N_, D_, nullptr);
      gemm_bt<0><<<dim3(D_/128,N_/128,8),256,0,stream>>>(BIG, XWT, N_,D_,N_, SP, nullptr, nullptr);
      u16* nxt = (l==0)? XA1 : (l==1)? YS : X1B;
      ln_epi512<<<N_/4,256,0,stream>>>(SP,PS_D,8, 512,0, nullptr, gb[gi],gg[gi],gbn[gi], nxt, nullptr);
      cur = nxt;
    }
  }

  gemm_bt<0><<<dim3(D_/128,N_/128,4),256,0,stream>>>(XA0, WT_nl0w2, N_,D_,D_, SP, nullptr, nullptr);
  bias_cast<<<(N_*D_/8)/256,256,0,stream>>>(SP,PS_D,4, nl0_b2, X0B);

  // cosine gram: balanced upper-triangle grid + min/max; upper-only binarize
  gemm_bt<1><<<dim3(1176,1,1),256,0,stream>>>(XNB, XNB, N_,N_,L_, BIG, MMX, nullptr);
  binarize_tri<<<N_,256,0,stream>>>(BIG, MMX, BM);
  binarize_fin<<<N_,256,0,stream>>>(BM, MMX, AGG, KI, Z);
  mirror_lower<<<dim3(N_/32, N_/32),256,0,stream>>>(BIG, MMX);   // dense only
  binarize_store<<<N_,256,0,stream>>>(BIG, MMX);                 // dense only

  // gc chain: sparse gather+LN fused (gated) with dense GEMM fallback
  {
    const u16* cur=X0B;
    for(int l=0;l<3;l++){
      int gi = l;
      gemm_bt<0><<<dim3(D_/128,N_/128,4),256,0,stream>>>(cur, WT_g[gi], N_,D_,D_, SP, nullptr, nullptr);
      transpose_sum_bf<<<dim3(D_/32, N_/32),256,0,stream>>>(SP, PS_D, 4, XWT, N_, D_, MMX);
      gemm_bt<0><<<dim3(D_/128,N_/128,8),256,0,stream>>>(BIG, XWT, N_,D_,N_, SP, nullptr, MMX);
      u16* nxt = (l==0)? XA1 : (l==1)? XA0 : X0B;
      gather_ln<<<N_,256,0,stream>>>(BM, SP, PS_D, 4, MMX, KI, gb[gi],gg[gi],gbn[gi], nxt);
      ln_epi512<<<N_/4,256,0,stream>>>(SP,PS_D,8, 512,0, KI, gb[gi],gg[gi],gbn[gi], nxt, MMX);
      cur = nxt;
    }
  }

  // pooling + head
  softmax_prep<<<1,1024,0,stream>>>(Z,E,SEXP);
  pooled_partial<<<32,256,0,stream>>>(E,X1B,X0B,PART);
  final_k<<<1,1024,0,stream>>>(PART,SEXP,ln_g,ln_b,cls_w,(float*)d_out);

  (void)in_sizes;(void)n_in;(void)out_size;(void)ws_size;
}

// Round 14
// 758.383 us; speedup vs baseline: 1.1236x; 1.0120x over previous
//
#include <hip/hip_runtime.h>

#define N_ 6144
#define L_ 1024
#define D_ 512
#define H_ 256
#define SPARSE_MAX 64u

typedef unsigned short u16;
typedef unsigned long long u64;
typedef __attribute__((ext_vector_type(4))) float f32x4;
typedef __attribute__((ext_vector_type(8))) short s16x8;
typedef __attribute__((ext_vector_type(4))) short s16x4;

__device__ __forceinline__ u16 f2b(float f){
  unsigned u = __float_as_uint(f);
  u += 0x7FFFu + ((u >> 16) & 1u);
  return (u16)(u >> 16);
}
__device__ __forceinline__ float b2f(u16 h){ return __uint_as_float(((unsigned)h) << 16); }
__device__ __forceinline__ unsigned fkey(float f){
  unsigned u = __float_as_uint(f);
  return (u & 0x80000000u) ? ~u : (u | 0x80000000u);
}
__device__ __forceinline__ float funkey(unsigned k){
  unsigned u = (k & 0x80000000u) ? (k & 0x7FFFFFFFu) : ~k;
  return __uint_as_float(u);
}
__device__ __forceinline__ float wave_sum(float v){
  #pragma unroll
  for(int o=32;o;o>>=1) v += __shfl_xor(v,o);
  return v;
}
__device__ __forceinline__ float wave_max(float v){
  #pragma unroll
  for(int o=32;o;o>>=1) v = fmaxf(v,__shfl_xor(v,o));
  return v;
}
__device__ __forceinline__ float wave_min(float v){
  #pragma unroll
  for(int o=32;o;o>>=1) v = fminf(v,__shfl_xor(v,o));
  return v;
}
__device__ __forceinline__ float blk_sum256(float v){
  __shared__ float sm[4];
  v = wave_sum(v);
  __syncthreads();
  if((threadIdx.x&63)==0) sm[threadIdx.x>>6]=v;
  __syncthreads();
  return sm[0]+sm[1]+sm[2]+sm[3];
}
__device__ __forceinline__ float blk_min256(float v){
  __shared__ float sm[4];
  v = wave_min(v);
  __syncthreads();
  if((threadIdx.x&63)==0) sm[threadIdx.x>>6]=v;
  __syncthreads();
  return fminf(fminf(sm[0],sm[1]),fminf(sm[2],sm[3]));
}
__device__ __forceinline__ float blk_max256(float v){
  __shared__ float sm[4];
  v = wave_max(v);
  __syncthreads();
  if((threadIdx.x&63)==0) sm[threadIdx.x>>6]=v;
  __syncthreads();
  return fmaxf(fmaxf(sm[0],sm[1]),fmaxf(sm[2],sm[3]));
}

// ---------------- 128x128 GEMM: C[M,Nc] = A @ Bt^T (bf16) ------------------
// 3-buffer staging, XCD-chunked swizzle, LDS-bounce epilogue, split-K planes.
// MODE 0: write bf16 plane z.  gate!=null && sparse -> early exit.
// MODE 1 (gram): BALANCED upper-triangle 1-D grid (1176 blocks, bijective
//                lid->(i<=j) map, XCD-chunked) + NT store + min/max atomics.
template<int VW> __device__ __forceinline__ void waitv(){
  if constexpr(VW==8) asm volatile("s_waitcnt vmcnt(8)" ::: "memory");
  else if constexpr(VW==4) asm volatile("s_waitcnt vmcnt(4)" ::: "memory");
  else asm volatile("s_waitcnt vmcnt(0)" ::: "memory");
}

#define STG4(bb,k0) do{ \
  __builtin_amdgcn_global_load_lds((__attribute__((address_space(1))) void*)(gA0+(k0)), (__attribute__((address_space(3))) void*)(lds + (bb)*4096 + (wid<<9)),        16, 0, 0); \
  __builtin_amdgcn_global_load_lds((__attribute__((address_space(1))) void*)(gA1+(k0)), (__attribute__((address_space(3))) void*)(lds + (bb)*4096 + 2048 + (wid<<9)), 16, 0, 0); \
  __builtin_amdgcn_global_load_lds((__attribute__((address_space(1))) void*)(gB0+(k0)), (__attribute__((address_space(3))) void*)(lds + 12288 + (bb)*4096 + (wid<<9)),        16, 0, 0); \
  __builtin_amdgcn_global_load_lds((__attribute__((address_space(1))) void*)(gB1+(k0)), (__attribute__((address_space(3))) void*)(lds + 12288 + (bb)*4096 + 2048 + (wid<<9)), 16, 0, 0); \
}while(0)

template<int MODE>
__global__ __launch_bounds__(256) void gemm_bt(
  const u16* __restrict__ A, const u16* __restrict__ Bt,
  int M, int Nc, int K,
  u16* __restrict__ Cb, unsigned* __restrict__ mmx,
  const unsigned* __restrict__ gate)
{
  if (gate && gate[2] <= SPARSE_MAX) return;
  __shared__ __align__(16) u16 lds[3*4096*2];   // 48 KB
  const int tid = threadIdx.x;
  const int wid = tid>>6, lane = tid&63;

  int m0, n0;
  if (MODE==1){
    // balanced upper-triangle map: 1176 blocks, XCD-chunked (1176 = 8*147)
    int t = (int)blockIdx.x;
    t = (t&7)*147 + (t>>3);
    int i=0, rem=t;
    while (rem >= 48-i){ rem -= 48-i; ++i; }
    m0 = i<<7; n0 = (i+rem)<<7;
  } else {
    const int gx = gridDim.x;
    int lid = blockIdx.y*gx + blockIdx.x;
    const int nwg = gx*gridDim.y;
    if ((nwg & 7) == 0) {
      const int chunk = nwg >> 3;
      lid = (lid & 7)*chunk + (lid >> 3);
    }
    m0 = (lid/gx)<<7; n0 = (lid%gx)<<7;
  }
  const int wr = wid>>1, wc = wid&1;

  const int Klen = K / gridDim.z;
  const int kbeg = blockIdx.z * Klen;

  const int srow = (wid<<4) + (lane>>2);
  const int scol = (lane&3)<<3;
  const u16* gA0 = A  + (size_t)(m0+srow   )*K + scol;
  const u16* gA1 = A  + (size_t)(m0+srow+64)*K + scol;
  const u16* gB0 = Bt + (size_t)(n0+srow   )*K + scol;
  const u16* gB1 = Bt + (size_t)(n0+srow+64)*K + scol;

  f32x4 acc[4][4] = {};
  const int lr = lane&15, lk = (lane>>4)<<3;

  const int NIT = Klen>>5;   // >= 3 required (all launches satisfy)
  STG4(0, kbeg);
  STG4(1, kbeg+32);
  STG4(2, kbeg+64);

  for (int it=0; it<NIT-2; ++it){
    const int b = it - (it/3)*3;
    waitv<8>();
    __builtin_amdgcn_s_barrier();
    const u16* baseA = lds + b*4096;
    const u16* baseB = lds + 12288 + b*4096;
    s16x8 af[4], bfr[4];
    #pragma unroll
    for(int m=0;m<4;m++) af[m]  = *(const s16x8*)(baseA + ((wr<<6)+(m<<4)+lr)*32 + lk);
    #pragma unroll
    for(int n=0;n<4;n++) bfr[n] = *(const s16x8*)(baseB + ((wc<<6)+(n<<4)+lr)*32 + lk);
    asm volatile("s_waitcnt lgkmcnt(0)" ::: "memory");
    __builtin_amdgcn_sched_barrier(0);
    __builtin_amdgcn_s_barrier();
    if (it+3 < NIT) STG4(b, kbeg + ((it+3)<<5));
    #pragma unroll
    for(int m=0;m<4;m++)
      #pragma unroll
      for(int n=0;n<4;n++)
        acc[m][n] = __builtin_amdgcn_mfma_f32_16x16x32_bf16(af[m], bfr[n], acc[m][n], 0,0,0);
  }
  {
    const int it = NIT-2; const int b = it - (it/3)*3;
    waitv<4>();
    __builtin_amdgcn_s_barrier();
    const u16* baseA = lds + b*4096;
    const u16* baseB = lds + 12288 + b*4096;
    s16x8 af[4], bfr[4];
    #pragma unroll
    for(int m=0;m<4;m++) af[m]  = *(const s16x8*)(baseA + ((wr<<6)+(m<<4)+lr)*32 + lk);
    #pragma unroll
    for(int n=0;n<4;n++) bfr[n] = *(const s16x8*)(baseB + ((wc<<6)+(n<<4)+lr)*32 + lk);
    #pragma unroll
    for(int m=0;m<4;m++)
      #pragma unroll
      for(int n=0;n<4;n++)
        acc[m][n] = __builtin_amdgcn_mfma_f32_16x16x32_bf16(af[m], bfr[n], acc[m][n], 0,0,0);
  }
  {
    const int it = NIT-1; const int b = it - (it/3)*3;
    waitv<0>();
    __builtin_amdgcn_s_barrier();
    const u16* baseA = lds + b*4096;
    const u16* baseB = lds + 12288 + b*4096;
    s16x8 af[4], bfr[4];
    #pragma unroll
    for(int m=0;m<4;m++) af[m]  = *(const s16x8*)(baseA + ((wr<<6)+(m<<4)+lr)*32 + lk);
    #pragma unroll
    for(int n=0;n<4;n++) bfr[n] = *(const s16x8*)(baseB + ((wc<<6)+(n<<4)+lr)*32 + lk);
    #pragma unroll
    for(int m=0;m<4;m++)
      #pragma unroll
      for(int n=0;n<4;n++)
        acc[m][n] = __builtin_amdgcn_mfma_f32_16x16x32_bf16(af[m], bfr[n], acc[m][n], 0,0,0);
  }

  // MODE 1: min/max from registers (before LDS reuse)
  float tmin = 3.0e38f, tmax = -3.0e38f;
  if (MODE==1){
    #pragma unroll
    for(int m=0;m<4;m++)
      #pragma unroll
      for(int n=0;n<4;n++){
        f32x4 v = acc[m][n];
        #pragma unroll
        for(int e=0;e<4;e++){ tmin = fminf(tmin,v[e]); tmax = fmaxf(tmax,v[e]); }
      }
  }

  __syncthreads();
  u16* lC = lds;
  {
    const int rb_l = (wr<<6) + ((lane>>4)<<2);
    const int cb_l = (wc<<6) + lr;
    #pragma unroll
    for(int m=0;m<4;m++)
      #pragma unroll
      for(int n=0;n<4;n++){
        f32x4 v = acc[m][n];
        #pragma unroll
        for(int e=0;e<4;e++)
          lC[(rb_l+(m<<4)+e)*128 + cb_l+(n<<4)] = f2b(v[e]);
      }
  }
  __syncthreads();
  u16* Cp = (MODE==0) ? (Cb + (size_t)blockIdx.z * M * Nc) : Cb;
  #pragma unroll
  for(int q=0;q<8;q++){
    int c = (q<<8) + tid;
    int r = c>>4, cc = (c&15)<<3;
    s16x8 v = *(const s16x8*)(lC + r*128 + cc);
    if (MODE==1)
      __builtin_nontemporal_store(v, (s16x8*)(Cp + (size_t)(m0+r)*Nc + n0 + cc));
    else
      *(s16x8*)(Cp + (size_t)(m0+r)*Nc + n0 + cc) = v;
  }

  if (MODE==1){
    tmin = wave_min(tmin); tmax = wave_max(tmax);
    __shared__ float rmn[4], rmx[4];
    if(lane==0){ rmn[wid]=tmin; rmx[wid]=tmax; }
    __syncthreads();
    if(tid==0){
      float mn=fminf(fminf(rmn[0],rmn[1]),fminf(rmn[2],rmn[3]));
      float mx=fmaxf(fmaxf(rmx[0],rmx[1]),fmaxf(rmx[2],rmx[3]));
      atomicMin(mmx+0, fkey(mn));
      atomicMax(mmx+1, fkey(mx));
    }
  }
}

// DENSE-FALLBACK ONLY: copy strictly-upper 128-blocks of C to lower, transposed.
// Grid: 48x48 128-block pairs; each block loops 4x4 32x32 subtiles.
__global__ __launch_bounds__(256) void mirror_lower(u16* __restrict__ C,
  const unsigned* __restrict__ gate)
{
  if (gate[2] <= SPARSE_MAX) return;
  if (blockIdx.y >= blockIdx.x) return;          // strictly-upper 128-blocks
  __shared__ u16 t[32][33];
  int tx = threadIdx.x&31, ty = threadIdx.x>>5;
  #pragma unroll
  for(int sr=0;sr<4;sr++)
    for(int sc=0;sc<4;sc++){
      int r0 = (blockIdx.y<<7) + (sr<<5);
      int c0 = (blockIdx.x<<7) + (sc<<5);
      __syncthreads();
      #pragma unroll
      for(int i=0;i<32;i+=8) t[ty+i][tx] = C[(size_t)(r0+ty+i)*N_ + c0+tx];
      __syncthreads();
      #pragma unroll
      for(int i=0;i<32;i+=8)
        __builtin_nontemporal_store(t[tx][ty+i], C + (size_t)(c0+ty+i)*N_ + r0+tx);
    }
}

// batched weight-prep transposes: fp32 [R][C] -> bf16 [C][R], 12 descriptors
struct TDesc { const float* src; u16* dst; int R; int C; int base; };
struct TDescs { TDesc d[12]; };
__global__ __launch_bounds__(256) void transpose_cast_multi(TDescs ds, int nd)
{
  int b = (int)blockIdx.x;
  int k = 0;
  for (int q=1;q<nd;q++) if (b >= ds.d[q].base) k = q;
  const float* src = ds.d[k].src;
  u16* dst = ds.d[k].dst;
  int R = ds.d[k].R, C = ds.d[k].C;
  int lt = b - ds.d[k].base;
  int tc = C>>5;
  int bx = lt % tc, by = lt / tc;
  __shared__ float t[32][33];
  int c0 = bx<<5, r0 = by<<5;
  int tx = threadIdx.x&31, ty = threadIdx.x>>5;
  #pragma unroll
  for(int i=0;i<32;i+=8) t[ty+i][tx] = src[(size_t)(r0+ty+i)*C + c0+tx];
  __syncthreads();
  #pragma unroll
  for(int i=0;i<32;i+=8) dst[(size_t)(c0+ty+i)*R + r0+tx] = f2b(t[tx][ty+i]);
}

// dst[C][R] bf16 = transpose( sum_p bf16_plane_p [R][C] ); gated (dense path)
__global__ __launch_bounds__(256) void transpose_sum_bf(
  const u16* __restrict__ src, size_t pstr, int nsp,
  u16* __restrict__ dst, int R, int C, const unsigned* __restrict__ gate)
{
  if (gate && gate[2] <= SPARSE_MAX) return;
  __shared__ float t[32][33];
  int c0 = blockIdx.x<<5, r0 = blockIdx.y<<5;
  int tx = threadIdx.x&31, ty = threadIdx.x>>5;
  #pragma unroll
  for(int i=0;i<32;i+=8){
    float v = 0;
    for(int p=0;p<nsp;p++)
      v += b2f(src[(size_t)p*pstr + (size_t)(r0+ty+i)*C + c0+tx]);
    t[ty+i][tx] = v;
  }
  __syncthreads();
  #pragma unroll
  for(int i=0;i<32;i+=8) dst[(size_t)(c0+ty+i)*R + r0+tx] = f2b(t[tx][ty+i]);
}

__global__ __launch_bounds__(256) void prep_x(const float* __restrict__ x,
  u16* __restrict__ xb, u16* __restrict__ xnb)
{
  int row = blockIdx.x, t = threadIdx.x;
  const float* p = x + (size_t)row*L_ + (t<<2);
  f32x4 v = *(const f32x4*)p;
  float ss = v[0]*v[0]+v[1]*v[1]+v[2]*v[2]+v[3]*v[3];
  float tot = blk_sum256(ss);
  float inv = 1.0f/fmaxf(sqrtf(tot), 1e-12f);
  u16* pb = xb  + (size_t)row*L_ + (t<<2);
  u16* pn = xnb + (size_t)row*L_ + (t<<2);
  #pragma unroll
  for(int k=0;k<4;k++){ pb[k]=f2b(v[k]); pn[k]=f2b(v[k]*inv); }
}

// fused-projection epilogue: a at cols [0,256), b at [256,512) of [N,1536] planes
__global__ __launch_bounds__(256) void attn_epi(const u16* __restrict__ SPA,
  size_t pstr, int nsp,
  const float* __restrict__ ba, const float* __restrict__ bb,
  const float* __restrict__ wc, const float* __restrict__ bc,
  float* __restrict__ agg, float* __restrict__ s)
{
  int row = (blockIdx.x<<2) + (threadIdx.x>>6);
  int lane = threadIdx.x&63;
  float a[4]={0,0,0,0}, b[4]={0,0,0,0};
  for(int p=0;p<nsp;p++){
    s16x4 ua = *(const s16x4*)(SPA + (size_t)p*pstr + (size_t)row*1536 + (lane<<2));
    s16x4 ub = *(const s16x4*)(SPA + (size_t)p*pstr + (size_t)row*1536 + 256 + (lane<<2));
    #pragma unroll
    for(int j=0;j<4;j++){ a[j]+=b2f((u16)ua[j]); b[j]+=b2f((u16)ub[j]); }
  }
  float acc=0;
  #pragma unroll
  for(int j=0;j<4;j++){
    int h = (lane<<2)+j;
    float tv = tanhf(a[j]+ba[h]);
    float sg = 1.0f/(1.0f+expf(-(b[j]+bb[h])));
    acc += tv*sg*wc[h];
  }
  acc = wave_sum(acc);
  if(lane==0){
    float v = acc + bc[0];
    agg[row]=v;
    s[row]=1.0f/(1.0f+expf(-v));
  }
}

// single-block min/max of s (no global atomic contention)
__global__ __launch_bounds__(256) void s_stats(const float* __restrict__ s, float* __restrict__ sc){
  int t=threadIdx.x;
  float mn=3e38f, mx=-3e38f;
  for(int i=t;i<N_;i+=256){ float v=s[i]; mn=fminf(mn,v); mx=fmaxf(mx,v); }
  float MN=blk_min256(mn);
  float MX=blk_max256(mx);
  if(t==0){ sc[0]=MN; sc[1]=MX; }
}

__global__ __launch_bounds__(256) void aw_write(const float* __restrict__ maps, const float* __restrict__ s,
  const float* __restrict__ sc, u16* __restrict__ awb)
{
  int i = blockIdx.x, t = threadIdx.x;
  float smin = sc[0], smax = sc[1];
  float mn = smin*smin, mx = smax*smax;
  float beta = 0.6f/(mx-mn);
  float c1 = 0.4f - beta*mn;
  float si = s[i];
  const float* mrow = maps + (size_t)i*N_;
  float mv[24];
  float part = 0;
  #pragma unroll
  for(int q=0;q<24;q++){
    int j = t + (q<<8);
    mv[q] = c1 + beta*si*s[j] + mrow[j];
    part += mv[q];
  }
  float r = blk_sum256(part);
  float inv = 1.0f/fmaxf(r, 1e-12f);
  u16* orow = awb + (size_t)i*N_;
  #pragma unroll
  for(int q=0;q<24;q++)
    __builtin_nontemporal_store(f2b(mv[q]*inv), orow + t + (q<<8));
}

// out = relu(LN( (sum_p Y_p)*rowscale + bias )).  Dense path only.
__global__ __launch_bounds__(256) void ln_epi512(const u16* __restrict__ Y, size_t pstr, int nsp,
  int rs, int cbase,
  const float* __restrict__ ki,
  const float* __restrict__ bias, const float* __restrict__ g, const float* __restrict__ bn,
  u16* __restrict__ outb,
  const unsigned* __restrict__ gate)
{
  if (gate && gate[2] <= SPARSE_MAX) return;
  int row = (blockIdx.x<<2)+(threadIdx.x>>6);
  int lane = threadIdx.x&63;
  int c0 = lane<<3;
  float v[8] = {0,0,0,0,0,0,0,0};
  for(int p=0;p<nsp;p++){
    s16x8 u = *(const s16x8*)(Y + (size_t)p*pstr + (size_t)row*rs + cbase + c0);
    #pragma unroll
    for(int j=0;j<8;j++) v[j] += b2f((u16)u[j]);
  }
  float scale = ki ? (1.0f/ki[row]) : 1.0f;
  float sum=0, ssum=0;
  #pragma unroll
  for(int j=0;j<8;j++){ v[j] = v[j]*scale + bias[c0+j]; sum+=v[j]; ssum+=v[j]*v[j]; }
  sum = wave_sum(sum); ssum = wave_sum(ssum);
  float m = sum*(1.0f/D_);
  float var = ssum*(1.0f/D_) - m*m;
  float invsd = rsqrtf(var + 1e-5f);
  u16 ob[8];
  #pragma unroll
  for(int j=0;j<8;j++){
    float o = (v[j]-m)*invsd*g[c0+j] + bn[c0+j];
    o = fmaxf(o, 0.0f);
    ob[j] = f2b(o);
  }
  *(s16x8*)(outb + (size_t)row*D_ + c0) = *(s16x8*)ob;
}

// both proj LNs in one launch: blockIdx.y==0 -> nl1 (cbase 1024), ==1 -> nl0 (512)
__global__ __launch_bounds__(256) void ln_epi_proj(const u16* __restrict__ Y, size_t pstr, int nsp,
  const float* __restrict__ b1, const float* __restrict__ g1, const float* __restrict__ n1, u16* __restrict__ o1,
  const float* __restrict__ b0, const float* __restrict__ g0, const float* __restrict__ n0, u16* __restrict__ o0)
{
  const int sel = blockIdx.y;
  const int cbase = sel ? 512 : 1024;
  const float* bias = sel ? b0 : b1;
  const float* g    = sel ? g0 : g1;
  const float* bn   = sel ? n0 : n1;
  u16* outb         = sel ? o0 : o1;
  int row = (blockIdx.x<<2)+(threadIdx.x>>6);
  int lane = threadIdx.x&63;
  int c0 = lane<<3;
  float v[8] = {0,0,0,0,0,0,0,0};
  for(int p=0;p<nsp;p++){
    s16x8 u = *(const s16x8*)(Y + (size_t)p*pstr + (size_t)row*1536 + cbase + c0);
    #pragma unroll
    for(int j=0;j<8;j++) v[j] += b2f((u16)u[j]);
  }
  float sum=0, ssum=0;
  #pragma unroll
  for(int j=0;j<8;j++){ v[j] = v[j] + bias[c0+j]; sum+=v[j]; ssum+=v[j]*v[j]; }
  sum = wave_sum(sum); ssum = wave_sum(ssum);
  float m = sum*(1.0f/D_);
  float var = ssum*(1.0f/D_) - m*m;
  float invsd = rsqrtf(var + 1e-5f);
  u16 ob[8];
  #pragma unroll
  for(int j=0;j<8;j++){
    float o = (v[j]-m)*invsd*g[c0+j] + bn[c0+j];
    o = fmaxf(o, 0.0f);
    ob[j] = f2b(o);
  }
  *(s16x8*)(outb + (size_t)row*D_ + c0) = *(s16x8*)ob;
}

__global__ __launch_bounds__(256) void bias_cast(const u16* __restrict__ Y, size_t pstr, int nsp,
  const float* __restrict__ b, u16* __restrict__ outb)
{
  size_t idx = ((size_t)blockIdx.x*256 + threadIdx.x)<<3;
  float v[8] = {0,0,0,0,0,0,0,0};
  for(int p=0;p<nsp;p++){
    s16x8 u = *(const s16x8*)(Y + (size_t)p*pstr + idx);
    #pragma unroll
    for(int j=0;j<8;j++) v[j] += b2f((u16)u[j]);
  }
  int c = (int)(idx & (D_-1));
  u16 ob[8];
  #pragma unroll
  for(int k=0;k<8;k++) ob[k] = f2b(v[k]+b[c+k]);
  *(s16x8*)(outb+idx) = *(s16x8*)ob;
}

__global__ void init_k(unsigned* mmx){
  mmx[0]=0xFFFFFFFFu; mmx[1]=0u; mmx[2]=0u;   // gram min/max, max-nnz (0 = sparse)
}

// upper-triangle binarize: scans only j>=i of the gram (lower half is stale).
// Writes bitmap: words > boundary via plain store; boundary word and rare
// mirrored bits (j>i) via atomicOr (idempotent -> deterministic). BM pre-zeroed.
__global__ __launch_bounds__(256) void binarize_tri(const u16* __restrict__ csb,
  const unsigned* __restrict__ mmx, u64* __restrict__ bm)
{
  int i = blockIdx.x, t = threadIdx.x;
  int lane = t&63, w = t>>6;
  float mn = funkey(mmx[0]), mx = funkey(mmx[1]);
  float th = mn + 0.5f*(mx-mn);
  const u16* row = csb + (size_t)i*N_;
  u64* bmrow = bm + (size_t)i*96;
  const int w0 = i>>6;                   // boundary word
  for (int wq = w0 + w; wq < 96; wq += 4){
    int j = (wq<<6) + lane;
    bool on = (j >= i) && (b2f(row[j]) >= th);
    u64 mask = __ballot(on);
    if (lane == 0){
      if (wq == w0) atomicOr((u64*)(bmrow+wq), mask);
      else bmrow[wq] = mask;
    }
    if (on && j > i)
      atomicOr((u64*)(bm + (size_t)j*96 + w0), 1ull << (i&63));
  }
}

// finalize from completed bitmap: ki, z, max-nnz (deterministic: fixed order)
__global__ __launch_bounds__(256) void binarize_fin(const u64* __restrict__ bm,
  unsigned* __restrict__ mmx, const float* __restrict__ agg,
  float* __restrict__ ki, float* __restrict__ z)
{
  int i = blockIdx.x, t = threadIdx.x;
  float cnt = 0, dot = 0;
  if (t < 96){
    u64 m = bm[(size_t)i*96 + t];
    cnt = (float)__popcll(m);
    while (m){
      int b = __ffsll((long long)m) - 1;
      m &= m - 1;
      dot += agg[(t<<6) + b];
    }
  }
  float k  = blk_sum256(cnt);
  float dt = blk_sum256(dot);
  if (t==0){
    ki[i] = k;
    float tr = dt/(k*sqrtf((float)N_));
    z[i] = 0.3f*tr + 0.7f*agg[i];
    if (k > (float)SPARSE_MAX)
      atomicMax(mmx+2, (unsigned)(k+0.5f));
  }
}

// dense-fallback only: rewrite BIG in place as 0/1 bf16 (after mirror_lower).
// Grid-stride over rows (256 blocks).
__global__ __launch_bounds__(256) void binarize_store(u16* __restrict__ csb,
  const unsigned* __restrict__ mmx)
{
  if (mmx[2] <= SPARSE_MAX) return;
  int t = threadIdx.x;
  float mn = funkey(mmx[0]), mx = funkey(mmx[1]);
  float th = mn + 0.5f*(mx-mn);
  for (int i = blockIdx.x; i < N_; i += 256){
    u16* row = csb + (size_t)i*N_;
    #pragma unroll
    for(int q=0;q<24;q++){
      int j = t + (q<<8);
      row[j] = (b2f(row[j]) >= th) ? (u16)0x3F80 : (u16)0;
    }
  }
}

// sparse adjacency apply FUSED with LN epilogue:
// row i: y = sum_{j: bit} sum_p SP[p][j,:]; out = relu(LN(y/ki + bias))
__global__ __launch_bounds__(256) void gather_ln(const u64* __restrict__ bm,
  const u16* __restrict__ SPp, size_t pstr, int nsp,
  const unsigned* __restrict__ gate, const float* __restrict__ ki,
  const float* __restrict__ bias, const float* __restrict__ g, const float* __restrict__ bn,
  u16* __restrict__ outb)
{
  if (gate[2] > SPARSE_MAX) return;
  int i = blockIdx.x, t = threadIdx.x;
  __shared__ u64 wbuf[96];
  __shared__ u16 idx[SPARSE_MAX];
  __shared__ int nn_s;
  if (t < 96) wbuf[t] = bm[(size_t)i*96 + t];
  __syncthreads();
  if (t == 0){
    int nn = 0;
    for(int k=0;k<96;k++){
      u64 m = wbuf[k];
      while(m && nn < (int)SPARSE_MAX){
        int b = __ffsll((long long)m) - 1;
        m &= m - 1;
        idx[nn++] = (u16)((k<<6) + b);
      }
    }
    nn_s = nn;
  }
  __syncthreads();
  int nn = nn_s;
  float a0=0, a1=0;
  for(int k=0;k<nn;k++){
    size_t jb = (size_t)idx[k]*512;
    for(int p=0;p<nsp;p++){
      a0 += b2f(SPp[p*pstr + jb + t]);
      a1 += b2f(SPp[p*pstr + jb + t + 256]);
    }
  }
  float scale = 1.0f/ki[i];
  float v0 = a0*scale + bias[t];
  float v1 = a1*scale + bias[t+256];
  float sum  = blk_sum256(v0+v1);
  float ssum = blk_sum256(v0*v0+v1*v1);
  float m = sum*(1.0f/512.0f);
  float var = ssum*(1.0f/512.0f) - m*m;
  float inv = rsqrtf(var+1e-5f);
  float o0 = fmaxf((v0-m)*inv*g[t]+bn[t], 0.0f);
  float o1 = fmaxf((v1-m)*inv*g[t+256]+bn[t+256], 0.0f);
  outb[(size_t)i*512 + t]       = f2b(o0);
  outb[(size_t)i*512 + t + 256] = f2b(o1);
}

__global__ __launch_bounds__(1024) void softmax_prep(const float* __restrict__ z,
  float* __restrict__ e, float* __restrict__ sexp)
{
  int t = threadIdx.x;
  __shared__ float sm[16];
  float mx=-3e38f;
  for(int i=t;i<N_;i+=1024) mx=fmaxf(mx,z[i]);
  mx = wave_max(mx);
  if((t&63)==0) sm[t>>6]=mx;
  __syncthreads();
  float zm = sm[0];
  #pragma unroll
  for(int w=1;w<16;w++) zm=fmaxf(zm,sm[w]);
  __syncthreads();
  float sum=0;
  for(int i=t;i<N_;i+=1024){ float ee=expf(z[i]-zm); e[i]=ee; sum+=ee; }
  sum = wave_sum(sum);
  if((t&63)==0) sm[t>>6]=sum;
  __syncthreads();
  if(t==0){ float S=0; for(int w=0;w<16;w++) S+=sm[w]; *sexp=S; }
}

// pooled partial sums over 192 rows/block; g2/g1 are bf16 [N,512]
__global__ __launch_bounds__(256) void pooled_partial(const float* __restrict__ e,
  const u16* __restrict__ g2b, const u16* __restrict__ g1b, float* __restrict__ part)
{
  int b = blockIdx.x, t = threadIdx.x;
  float a0=0,a1=0,a2=0,a3=0;
  for(int r=0;r<192;r++){
    int row = b*192+r;
    float w = e[row];
    a0 += w * b2f(g2b[(size_t)row*D_ + t]);
    a1 += w * b2f(g2b[(size_t)row*D_ + t+256]);
    a2 += w * b2f(g1b[(size_t)row*D_ + t]);
    a3 += w * b2f(g1b[(size_t)row*D_ + t+256]);
  }
  part[(size_t)b*1024 + t]      = a0;
  part[(size_t)b*1024 + t+256]  = a1;
  part[(size_t)b*1024 + t+512]  = a2;
  part[(size_t)b*1024 + t+768]  = a3;
}

__global__ __launch_bounds__(1024) void final_k(const float* __restrict__ part, const float* __restrict__ sexp,
  const float* __restrict__ lng, const float* __restrict__ lnb,
  const float* __restrict__ clsw, float* __restrict__ out)
{
  int t = threadIdx.x;
  __shared__ float red[16];
  __shared__ float smv[1024];
  __shared__ float lgs[4];
  float p=0;
  for(int b=0;b<32;b++) p += part[b*1024 + t];
  p /= sexp[0];
  float w = wave_sum(p);
  if((t&63)==0) red[t>>6]=w;
  __syncthreads();
  float tot=0;
  #pragma unroll
  for(int i2=0;i2<16;i2++) tot+=red[i2];
  float m = tot*(1.0f/1024.0f);
  __syncthreads();
  float d = p-m;
  w = wave_sum(d*d);
  if((t&63)==0) red[t>>6]=w;
  __syncthreads();
  tot=0;
  #pragma unroll
  for(int i2=0;i2<16;i2++) tot+=red[i2];
  float var = tot*(1.0f/1024.0f);
  float y = d*rsqrtf(var+1e-5f)*lng[t] + lnb[t];
  smv[t]=y;
  __syncthreads();
  if(t<4){
    float lg=0;
    for(int j=0;j<1024;j++) lg += smv[j]*clsw[j*4+t];
    lgs[t]=lg;
  }
  __syncthreads();
  if(t==0){
    float h[4];
    int am=0; float best=lgs[0];
    #pragma unroll
    for(int c2=0;c2<4;c2++){ h[c2]=1.0f/(1.0f+expf(-lgs[c2])); if(lgs[c2]>best){best=lgs[c2];am=c2;} }
    float sv=1.0f;
    #pragma unroll
    for(int c2=0;c2<4;c2++){ out[c2]=h[c2]; sv*=(1.0f-h[c2]); out[4+c2]=sv; }
    out[8]=(float)am;
  }
}

extern "C" void kernel_launch(void* const* d_in, const int* in_sizes, int n_in,
                              void* d_out, int out_size, void* d_ws, size_t ws_size,
                              hipStream_t stream)
{
  const float* x_path =(const float*)d_in[0];
  const float* maps   =(const float*)d_in[1];
  const float* nl0_w1 =(const float*)d_in[2];
  const float* nl0_b1 =(const float*)d_in[3];
  const float* nl0_g  =(const float*)d_in[4];
  const float* nl0_bn =(const float*)d_in[5];
  const float* nl0_w2 =(const float*)d_in[6];
  const float* nl0_b2 =(const float*)d_in[7];
  const float* nl1_w1 =(const float*)d_in[8];
  const float* nl1_b1 =(const float*)d_in[9];
  const float* nl1_g  =(const float*)d_in[10];
  const float* nl1_bn =(const float*)d_in[11];
  const float* nl1_w2 =(const float*)d_in[12];
  const float* nl1_b2 =(const float*)d_in[13];
  const float *gw[6], *gb[6], *gg[6], *gbn[6];   // gc0,gc1,gc2,ga0,ga1,ga2
  for(int l=0;l<6;l++){
    gw[l]  = (const float*)d_in[14+l*4+0];
    gb[l]  = (const float*)d_in[14+l*4+1];
    gg[l]  = (const float*)d_in[14+l*4+2];
    gbn[l] = (const float*)d_in[14+l*4+3];
  }
  const float* attn_wa=(const float*)d_in[38];
  const float* attn_ba=(const float*)d_in[39];
  const float* attn_wb=(const float*)d_in[40];
  const float* attn_bb=(const float*)d_in[41];
  const float* attn_wc=(const float*)d_in[42];
  const float* attn_bc=(const float*)d_in[43];
  const float* cls_w  =(const float*)d_in[44];
  const float* ln_g   =(const float*)d_in[45];
  const float* ln_b   =(const float*)d_in[46];

  char* ws=(char*)d_ws;
  size_t off=0;
  auto alc=[&](size_t b)->char*{ char* p=ws+off; off=(off+b+255)&~(size_t)255; return p; };
  u16* BIG = (u16*)alc((size_t)N_*N_*2);          // aw, then cs gram (time-shared)
  u16* XB  = (u16*)alc((size_t)N_*L_*2);
  u16* XNB = (u16*)alc((size_t)N_*L_*2);
  u16* WT_proj=(u16*)alc((size_t)1536*L_*2);      // [wa;wb;nl0w1;nl1w1] transposed
  u16* WT_nl0w2=(u16*)alc((size_t)D_*D_*2);
  u16* WT_nl1w2=(u16*)alc((size_t)D_*D_*2);
  u16* WT_g[6];
  for(int l=0;l<6;l++) WT_g[l]=(u16*)alc((size_t)D_*D_*2);
  u16* SP = (u16*)alc((size_t)8*N_*D_*2);         // planes: proj SK2 or 8x[N,512]
  u16* XWT=(u16*)alc((size_t)D_*N_*2);
  u16* XA0=(u16*)alc((size_t)N_*D_*2);
  u16* XA1=(u16*)alc((size_t)N_*D_*2);
  u16* X0B=(u16*)alc((size_t)N_*D_*2);
  u16* X1B=(u16*)alc((size_t)N_*D_*2);
  u16* YS =(u16*)alc((size_t)N_*D_*2);
  u64* BM =(u64*)alc((size_t)N_*96*8);
  float* PART=(float*)alc((size_t)32*1024*4);
  float* AGG=(float*)alc(N_*4);
  float* SS =(float*)alc(N_*4);
  float* KI =(float*)alc(N_*4);
  float* Z  =(float*)alc(N_*4);
  float* E  =(float*)alc(N_*4);
  float* SC =(float*)alc(256);
  unsigned* MMX=(unsigned*)alc(256);
  float* SEXP=(float*)alc(256);

  const size_t PS_D = (size_t)N_*D_;      // 512-col plane stride
  const size_t PS_P = (size_t)N_*1536;    // proj plane stride

  init_k<<<1,1,0,stream>>>(MMX);
  hipMemsetAsync(BM, 0, (size_t)N_*96*8, stream);
  prep_x<<<N_,256,0,stream>>>(x_path, XB, XNB);

  // batched weight prep (12 transposes in one launch)
  {
    TDescs ds;
    int base = 0;
    auto add=[&](int k, const float* s, u16* d, int R, int C){
      ds.d[k] = {s, d, R, C, base};
      base += (R>>5)*(C>>5);
    };
    add(0,  attn_wa, WT_proj,                   L_, H_);
    add(1,  attn_wb, WT_proj + (size_t)256*L_,  L_, H_);
    add(2,  nl0_w1,  WT_proj + (size_t)512*L_,  L_, D_);
    add(3,  nl1_w1,  WT_proj + (size_t)1024*L_, L_, D_);
    add(4,  nl0_w2,  WT_nl0w2, D_, D_);
    add(5,  nl1_w2,  WT_nl1w2, D_, D_);
    for(int l=0;l<6;l++) add(6+l, gw[l], WT_g[l], D_, D_);
    transpose_cast_multi<<<base,256,0,stream>>>(ds, 12);
  }

  // fused X projections: [a|b|h0|h1] = XB @ WT_proj^T  (SK=2)
  gemm_bt<0><<<dim3(1536/128, N_/128, 2),256,0,stream>>>(XB, WT_proj, N_, 1536, L_, SP, nullptr, nullptr);
  attn_epi<<<N_/4,256,0,stream>>>(SP, PS_P, 2, attn_ba, attn_bb, attn_wc, attn_bc, AGG, SS);
  s_stats<<<1,256,0,stream>>>(SS,SC);
  aw_write<<<N_,256,0,stream>>>(maps,SS,SC,BIG);

  // both proj LNs in one launch
  ln_epi_proj<<<dim3(N_/4,2),256,0,stream>>>(SP,PS_P,2,
    nl1_b1,nl1_g,nl1_bn,XA1, nl0_b1,nl0_g,nl0_bn,XA0);

  gemm_bt<0><<<dim3(D_/128,N_/128,4),256,0,stream>>>(XA1, WT_nl1w2, N_,D_,D_, SP, nullptr, nullptr);
  bias_cast<<<(N_*D_/8)/256,256,0,stream>>>(SP,PS_D,4, nl1_b2, X1B);

  // ga chain (dense adjacency = BIG = aw); adjacency GEMM split-K=8
  {
    const u16* cur=X1B;
    for(int l=0;l<3;l++){
      int gi = 3+l;
      gemm_bt<0><<<dim3(D_/128,N_/128,4),256,0,stream>>>(cur, WT_g[gi], N_,D_,D_, SP, nullptr, nullptr);
      transpose_sum_bf<<<dim3(D_/32, N_/32),256,0,stream>>>(SP, PS_D, 4, XWT, N_, D_, nullptr);
      gemm_bt<0><<<dim3(D_/128,N_/128,8),256,0,stream>>>(BIG, XWT, N_,D_,N_, SP, nullptr, nullptr);
      u16* nxt = (l==0)? XA1 : (l==1)? YS : X1B;
      ln_epi512<<<N_/4,256,0,stream>>>(SP,PS_D,8, 512,0, nullptr, gb[gi],gg[gi],gbn[gi], nxt, nullptr);
      cur = nxt;
    }
  }

  gemm_bt<0><<<dim3(D_/128,N_/128,4),256,0,stream>>>(XA0, WT_nl0w2, N_,D_,D_, SP, nullptr, nullptr);
  bias_cast<<<(N_*D_/8)/256,256,0,stream>>>(SP,PS_D,4, nl0_b2, X0B);

  // cosine gram: balanced upper-triangle grid + min/max; upper-only binarize
  gemm_bt<1><<<dim3(1176,1,1),256,0,stream>>>(XNB, XNB, N_,N_,L_, BIG, MMX, nullptr);
  binarize_tri<<<N_,256,0,stream>>>(BIG, MMX, BM);
  binarize_fin<<<N_,256,0,stream>>>(BM, MMX, AGG, KI, Z);
  mirror_lower<<<dim3(48, 48),256,0,stream>>>(BIG, MMX);   // dense only
  binarize_store<<<256,256,0,stream>>>(BIG, MMX);          // dense only

  // gc chain: sparse gather+LN fused (gated) with dense GEMM fallback
  {
    const u16* cur=X0B;
    for(int l=0;l<3;l++){
      int gi = l;
      gemm_bt<0><<<dim3(D_/128,N_/128,4),256,0,stream>>>(cur, WT_g[gi], N_,D_,D_, SP, nullptr, nullptr);
      transpose_sum_bf<<<dim3(D_/32, N_/32),256,0,stream>>>(SP, PS_D, 4, XWT, N_, D_, MMX);
      gemm_bt<0><<<dim3(D_/128,N_/128,8),256,0,stream>>>(BIG, XWT, N_,D_,N_, SP, nullptr, MMX);
      u16* nxt = (l==0)? XA1 : (l==1)? XA0 : X0B;
      gather_ln<<<N_,256,0,stream>>>(BM, SP, PS_D, 4, MMX, KI, gb[gi],gg[gi],gbn[gi], nxt);
      ln_epi512<<<N_/4,256,0,stream>>>(SP,PS_D,8, 512,0, KI, gb[gi],gg[gi],gbn[gi], nxt, MMX);
      cur = nxt;
    }
  }

  // pooling + head
  softmax_prep<<<1,1024,0,stream>>>(Z,E,SEXP);
  pooled_partial<<<32,256,0,stream>>>(E,X1B,X0B,PART);
  final_k<<<1,1024,0,stream>>>(PART,SEXP,ln_g,ln_b,cls_w,(float*)d_out);

  (void)in_sizes;(void)n_in;(void)out_size;(void)ws_size;
}